// Round 3
// baseline (707.182 us; speedup 1.0000x reference)
//
#include <hip/hip_runtime.h>
#include <math.h>

#define HID   128
#define NNODE 50000
#define NEDGE 800000
#define EB    64
#define P1    296   // edge featA pitch (shorts)
#define P2    152   // bf16 activation pitch (shorts)
#define PN    392   // node featA pitch (shorts): [h | agg_hi | agg_lo]
#define PMF   132   // fp32 m pitch (dwords) for reduction stage

typedef __attribute__((ext_vector_type(8))) short short8;
typedef __attribute__((ext_vector_type(4))) float f32x4;

__device__ __forceinline__ float silu_f(float x) { return x / (1.0f + __expf(-x)); }

__device__ __forceinline__ unsigned short f2bf(float f) {      // RNE
    unsigned int u = __float_as_uint(f);
    u += 0x7FFFu + ((u >> 16) & 1u);
    return (unsigned short)(u >> 16);
}
__device__ __forceinline__ float bf2f(unsigned short s) {
    return __uint_as_float(((unsigned int)s) << 16);
}

// ws layout (bytes):
//   0        : weights bf16 frag-major, 16896 units x 16B = 270336
//   270336   : h_bf16 [N*HID shorts] = 12.8MB
//   13070336 : deg    [N int]
//   13270336 : rowptr [N int]
//   13470336 : cursor [N int]
//   13670336 : bsum   [256 int]
//   13671360 : perm   [E int]
#define WS_HBF  270336
#define WS_DEG  13070336
#define WS_ROW  13270336
#define WS_CUR  13470336
#define WS_BSUM 13670336
#define WS_PERM 13671360

// ------------------------------------------------------------------ prep: weights->bf16 frags, h->bf16, zero deg
__global__ void egnn_prep(const float* eW1, const float* eW2, const float* cW1,
                          const float* nW1, const float* nW2, const float* h,
                          short* wsw, short* hbf, int* deg)
{
    int g = blockIdx.x * 256 + threadIdx.x;
    if (g < 16896) {
        const float* src; short* dst; int u, Kr, KC, isN1 = 0;
        if (g < 4608)       { src = eW1; dst = wsw;            u = g;         Kr = 258; KC = 9; }
        else if (g < 6656)  { src = eW2; dst = wsw + 4608*8;   u = g - 4608;  Kr = 128; KC = 4; }
        else if (g < 8704)  { src = cW1; dst = wsw + 6656*8;   u = g - 6656;  Kr = 128; KC = 4; }
        else if (g < 14848) { src = nW1; dst = wsw + 8704*8;   u = g - 8704;  Kr = 384; KC = 12; isN1 = 1; }
        else                { src = nW2; dst = wsw + 14848*8;  u = g - 14848; Kr = 128; KC = 4; }
        int nt   = u / (KC * 64);
        int rem  = u % (KC * 64);
        int kc   = rem >> 6;
        int lane = rem & 63;
        int n    = nt * 16 + (lane & 15);
        int kb   = kc * 32 + ((lane >> 4) & 3) * 8;
        short8 o;
#pragma unroll
        for (int j = 0; j < 8; ++j) {
            int k = kb + j;
            int ks = (isN1 && k >= 256) ? (k - 128) : k;
            float v = (k < Kr) ? src[(long)ks * HID + n] : 0.0f;
            o[j] = (short)f2bf(v);
        }
        *(short8*)&dst[(long)u * 8] = o;
    } else if (g < 16896 + 800000) {
        long i = (long)(g - 16896) * 8;
        const float4 v0 = *(const float4*)&h[i];
        const float4 v1 = *(const float4*)&h[i + 4];
        short8 o;
        o[0] = (short)f2bf(v0.x); o[1] = (short)f2bf(v0.y);
        o[2] = (short)f2bf(v0.z); o[3] = (short)f2bf(v0.w);
        o[4] = (short)f2bf(v1.x); o[5] = (short)f2bf(v1.y);
        o[6] = (short)f2bf(v1.z); o[7] = (short)f2bf(v1.w);
        *(short8*)&hbf[i] = o;
    } else {
        int i = g - 16896 - 800000;
        if (i < NNODE) deg[i] = 0;
    }
}

// ------------------------------------------------------------------ CSR build
__global__ void egnn_hist(const int* eidx, int* deg)
{
    int e = blockIdx.x * 256 + threadIdx.x;
    if (e < NEDGE) atomicAdd(&deg[eidx[e]], 1);
}

__global__ void egnn_scan1(const int* deg, int* rowptr, int* bsum)
{
    __shared__ int s[256];
    int t = threadIdx.x, i = blockIdx.x * 256 + t;
    int v = (i < NNODE) ? deg[i] : 0;
    s[t] = v; __syncthreads();
    for (int o = 1; o < 256; o <<= 1) {
        int x = (t >= o) ? s[t - o] : 0;
        __syncthreads(); s[t] += x; __syncthreads();
    }
    if (i < NNODE) rowptr[i] = s[t] - v;
    if (t == 255) bsum[blockIdx.x] = s[t];
}
__global__ void egnn_scan2(int* bsum)
{
    __shared__ int s[256];
    int t = threadIdx.x;
    int v = (t < 196) ? bsum[t] : 0;
    s[t] = v; __syncthreads();
    for (int o = 1; o < 256; o <<= 1) {
        int x = (t >= o) ? s[t - o] : 0;
        __syncthreads(); s[t] += x; __syncthreads();
    }
    if (t < 196) bsum[t] = s[t] - v;
}
__global__ void egnn_scan3(int* rowptr, const int* bsum, int* cursor)
{
    int i = blockIdx.x * 256 + threadIdx.x;
    if (i < NNODE) {
        int r = rowptr[i] + bsum[blockIdx.x];
        rowptr[i] = r; cursor[i] = r;
    }
}
__global__ void egnn_scatter(const int* eidx, int* cursor, int* perm)
{
    int e = blockIdx.x * 256 + threadIdx.x;
    if (e < NEDGE) {
        int p = atomicAdd(&cursor[eidx[e]], 1);
        perm[p] = e;
    }
}

// ------------------------------------------------------------------ init: zero agg (h_new region), copy pos
__global__ void egnn_init(const float* pos, float* out)
{
    long i = (long)blockIdx.x * 256 + threadIdx.x;
    if (i < (long)NNODE * HID) out[i] = 0.0f;
    if (i < (long)NNODE * 3)   out[(long)NNODE * HID + i] = pos[i];
}

// ------------------------------------------------------------------ edge phase
__global__ __launch_bounds__(256)
void egnn_edge(const short* hbf, const float* pos, const float* ea, const int* eidx,
               const int* perm,
               const float* eb1, const float* eb2, const float* cb1,
               const float* cW2, const float* cb2,
               const short* eW1f, const short* eW2f, const short* cW1f,
               float* aggout, float* outpos)
{
    __shared__ __align__(16) short sA[EB * P1];   // staged feats -> m bf16 -> m fp32 (PMF)
    __shared__ __align__(16) short sB[EB * P2];
    __shared__ int   eids[EB];
    __shared__ int   rci[2 * EB];
    __shared__ float rad[EB][4];
    __shared__ float part[EB][4];

    const int t  = threadIdx.x;
    const int e0 = blockIdx.x * EB;

    if (t < EB) eids[t] = perm[e0 + t];
    __syncthreads();
    if (t < 2 * EB) {
        int e = t & (EB - 1);
        rci[t] = (t < EB) ? eidx[eids[e]] : eidx[NEDGE + eids[e]];
    }
    __syncthreads();

    // ---- stage [h[row] | h[col]] from pre-converted bf16 ----
    for (int i = t; i < EB * 32; i += 256) {
        int e = i >> 5, u = i & 31;
        int nd = (u < 16) ? rci[e] : rci[EB + e];
        int uu = u & 15;
        uint4 v = *(const uint4*)&hbf[(long)nd * HID + uu * 8];
        *(uint4*)&sA[e * P1 + ((u < 16) ? 0 : HID) + uu * 8] = v;
    }
    if (t < EB) {
        int r = rci[t], c = rci[EB + t];
        float dx = pos[(long)r * 3 + 0] - pos[(long)c * 3 + 0];
        float dy = pos[(long)r * 3 + 1] - pos[(long)c * 3 + 1];
        float dz = pos[(long)r * 3 + 2] - pos[(long)c * 3 + 2];
        float rn = fmaxf(sqrtf(dx * dx + dy * dy + dz * dz), 1e-8f);
        rad[t][0] = dx; rad[t][1] = dy; rad[t][2] = dz; rad[t][3] = rn;
        sA[t * P1 + 256] = (short)f2bf(rn);
        sA[t * P1 + 257] = (short)f2bf(ea[eids[t]]);
        unsigned int* z = (unsigned int*)sA;     // zero k=258..287 (MFMA pad)
        for (int zz = 0; zz < 15; ++zz) z[148 * t + 129 + zz] = 0u;
    }
    __syncthreads();

    const int lane = t & 63;
    const int w    = t >> 6;
    const int l15  = lane & 15;
    const int q    = lane >> 4;
    const int ns   = w * 32;

    f32x4 acc[2][4];
    short8 a[4], b[2];
    float mreg[2][4][4];

    // ---- GEMM1: [64x288]bf16 @ eW1f -> silu -> sB ----
#pragma unroll
    for (int nt = 0; nt < 2; ++nt) {
        float bv = eb1[ns + nt * 16 + l15];
#pragma unroll
        for (int mt = 0; mt < 4; ++mt)
            for (int r = 0; r < 4; ++r) acc[nt][mt][r] = bv;
    }
    for (int kc = 0; kc < 9; ++kc) {
#pragma unroll
        for (int mt = 0; mt < 4; ++mt)
            a[mt] = *(const short8*)&sA[(mt * 16 + l15) * P1 + kc * 32 + q * 8];
#pragma unroll
        for (int nt = 0; nt < 2; ++nt)
            b[nt] = *(const short8*)&eW1f[(((w * 2 + nt) * 9 + kc) * 64 + lane) * 8];
#pragma unroll
        for (int nt = 0; nt < 2; ++nt)
#pragma unroll
            for (int mt = 0; mt < 4; ++mt)
                acc[nt][mt] = __builtin_amdgcn_mfma_f32_16x16x32_bf16(a[mt], b[nt], acc[nt][mt], 0, 0, 0);
    }
#pragma unroll
    for (int nt = 0; nt < 2; ++nt)
#pragma unroll
        for (int mt = 0; mt < 4; ++mt)
            for (int r = 0; r < 4; ++r)
                sB[(mt * 16 + q * 4 + r) * P2 + ns + nt * 16 + l15] = (short)f2bf(silu_f(acc[nt][mt][r]));
    __syncthreads();

    // ---- GEMM2: sB @ eW2f -> silu = m; fp32 m to regs, bf16 m into sA ----
#pragma unroll
    for (int nt = 0; nt < 2; ++nt) {
        float bv = eb2[ns + nt * 16 + l15];
#pragma unroll
        for (int mt = 0; mt < 4; ++mt)
            for (int r = 0; r < 4; ++r) acc[nt][mt][r] = bv;
    }
    for (int kc = 0; kc < 4; ++kc) {
#pragma unroll
        for (int mt = 0; mt < 4; ++mt)
            a[mt] = *(const short8*)&sB[(mt * 16 + l15) * P2 + kc * 32 + q * 8];
#pragma unroll
        for (int nt = 0; nt < 2; ++nt)
            b[nt] = *(const short8*)&eW2f[(((w * 2 + nt) * 4 + kc) * 64 + lane) * 8];
#pragma unroll
        for (int nt = 0; nt < 2; ++nt)
#pragma unroll
            for (int mt = 0; mt < 4; ++mt)
                acc[nt][mt] = __builtin_amdgcn_mfma_f32_16x16x32_bf16(a[mt], b[nt], acc[nt][mt], 0, 0, 0);
    }
    {
        short* sA2 = sA;   // GEMM1 input dead; reuse for bf16 m at pitch P2
#pragma unroll
        for (int nt = 0; nt < 2; ++nt)
#pragma unroll
            for (int mt = 0; mt < 4; ++mt)
                for (int r = 0; r < 4; ++r) {
                    float v = silu_f(acc[nt][mt][r]);
                    mreg[nt][mt][r] = v;
                    sA2[(mt * 16 + q * 4 + r) * P2 + ns + nt * 16 + l15] = (short)f2bf(v);
                }
    }
    __syncthreads();

    // ---- GEMM3: m @ cW1f -> silu -> dot(cW2) ----
#pragma unroll
    for (int nt = 0; nt < 2; ++nt) {
        float bv = cb1[ns + nt * 16 + l15];
#pragma unroll
        for (int mt = 0; mt < 4; ++mt)
            for (int r = 0; r < 4; ++r) acc[nt][mt][r] = bv;
    }
    for (int kc = 0; kc < 4; ++kc) {
#pragma unroll
        for (int mt = 0; mt < 4; ++mt)
            a[mt] = *(const short8*)&sA[(mt * 16 + l15) * P2 + kc * 32 + q * 8];
#pragma unroll
        for (int nt = 0; nt < 2; ++nt)
            b[nt] = *(const short8*)&cW1f[(((w * 2 + nt) * 4 + kc) * 64 + lane) * 8];
#pragma unroll
        for (int nt = 0; nt < 2; ++nt)
#pragma unroll
            for (int mt = 0; mt < 4; ++mt)
                acc[nt][mt] = __builtin_amdgcn_mfma_f32_16x16x32_bf16(a[mt], b[nt], acc[nt][mt], 0, 0, 0);
    }
    {
        float cw0 = cW2[ns + l15];
        float cw1 = cW2[ns + 16 + l15];
#pragma unroll
        for (int mt = 0; mt < 4; ++mt) {
            float p[4];
            for (int r = 0; r < 4; ++r)
                p[r] = silu_f(acc[0][mt][r]) * cw0 + silu_f(acc[1][mt][r]) * cw1;
            for (int mask = 1; mask < 16; mask <<= 1)
                for (int r = 0; r < 4; ++r) p[r] += __shfl_xor(p[r], mask);
            if (l15 == 0)
                for (int r = 0; r < 4; ++r) part[mt * 16 + q * 4 + r][w] = p[r];
        }
    }
    __syncthreads();   // GEMM3 reads of sA done; part complete

    // ---- dump fp32 m to LDS for run-merged reduction ----
    {
        float* sMf = (float*)sA;
#pragma unroll
        for (int nt = 0; nt < 2; ++nt)
#pragma unroll
            for (int mt = 0; mt < 4; ++mt)
                for (int r = 0; r < 4; ++r)
                    sMf[(mt * 16 + q * 4 + r) * PMF + ns + nt * 16 + l15] = mreg[nt][mt][r];
    }
    __syncthreads();

    // ---- pos atomics (sorted rows -> low contention) ----
    if (t < EB) {
        float cd  = part[t][0] + part[t][1] + part[t][2] + part[t][3] + cb2[0];
        float inv = cd / rad[t][3];
        int r = rci[t];
        atomicAdd(&outpos[(long)r * 3 + 0], inv * rad[t][0]);
        atomicAdd(&outpos[(long)r * 3 + 1], inv * rad[t][1]);
        atomicAdd(&outpos[(long)r * 3 + 2], inv * rad[t][2]);
    }

    // ---- agg: run-merged atomics (rows sorted within block) ----
    {
        const float* sMf = (const float*)sA;
        int j = t >> 1, k = t & 1;
        float s = 0.0f;
        int prev = rci[32 * k];
        for (int e = 32 * k; e < 32 * k + 32; ++e) {
            int rr = rci[e];
            if (rr != prev) {
                atomicAdd(&aggout[(long)prev * HID + j], s);
                s = 0.0f; prev = rr;
            }
            s += sMf[e * PMF + j];
        }
        atomicAdd(&aggout[(long)prev * HID + j], s);
    }
}

// ------------------------------------------------------------------ node phase (agg aliases out h-region)
__global__ __launch_bounds__(256)
void egnn_node(const float* h, const short* hbf, const float* agg,
               const float* nb1, const float* nb2,
               const short* nW1f, const short* nW2f,
               float* out)
{
    __shared__ __align__(16) short sA[EB * PN];   // [h | agg_hi | agg_lo]
    __shared__ __align__(16) short sB[EB * P2];

    const int t  = threadIdx.x;
    const int n0 = blockIdx.x * EB;

    for (int i = t; i < EB * 16; i += 256) {      // h part from pre-converted bf16
        int e = i >> 4, uu = i & 15;
        int nd = n0 + e; if (nd >= NNODE) nd = NNODE - 1;
        *(uint4*)&sA[e * PN + uu * 8] = *(const uint4*)&hbf[(long)nd * HID + uu * 8];
    }
    for (int i = t; i < EB * 32; i += 256) {      // agg hi/lo split
        int e = i >> 5, uu = i & 31;
        int nd = n0 + e; if (nd >= NNODE) nd = NNODE - 1;
        const float4 v = *(const float4*)&agg[(long)nd * HID + uu * 4];
        unsigned short hx = f2bf(v.x), hy = f2bf(v.y), hz = f2bf(v.z), hw = f2bf(v.w);
        *(uint2*)&sA[e * PN + HID + uu * 4] =
            make_uint2(hx | ((unsigned int)hy << 16), hz | ((unsigned int)hw << 16));
        unsigned int l0 = f2bf(v.x - bf2f(hx)) | ((unsigned int)f2bf(v.y - bf2f(hy)) << 16);
        unsigned int l1 = f2bf(v.z - bf2f(hz)) | ((unsigned int)f2bf(v.w - bf2f(hw)) << 16);
        *(uint2*)&sA[e * PN + 2 * HID + uu * 4] = make_uint2(l0, l1);
    }
    __syncthreads();

    const int lane = t & 63;
    const int w    = t >> 6;
    const int l15  = lane & 15;
    const int q    = lane >> 4;
    const int ns   = w * 32;

    f32x4 acc[2][4];
    short8 a[4], b[2];

    // ---- GEMM1: [64x384] @ nW1f -> silu -> sB ----
#pragma unroll
    for (int nt = 0; nt < 2; ++nt) {
        float bv = nb1[ns + nt * 16 + l15];
#pragma unroll
        for (int mt = 0; mt < 4; ++mt)
            for (int r = 0; r < 4; ++r) acc[nt][mt][r] = bv;
    }
    for (int kc = 0; kc < 12; ++kc) {
#pragma unroll
        for (int mt = 0; mt < 4; ++mt)
            a[mt] = *(const short8*)&sA[(mt * 16 + l15) * PN + kc * 32 + q * 8];
#pragma unroll
        for (int nt = 0; nt < 2; ++nt)
            b[nt] = *(const short8*)&nW1f[(((w * 2 + nt) * 12 + kc) * 64 + lane) * 8];
#pragma unroll
        for (int nt = 0; nt < 2; ++nt)
#pragma unroll
            for (int mt = 0; mt < 4; ++mt)
                acc[nt][mt] = __builtin_amdgcn_mfma_f32_16x16x32_bf16(a[mt], b[nt], acc[nt][mt], 0, 0, 0);
    }
#pragma unroll
    for (int nt = 0; nt < 2; ++nt)
#pragma unroll
        for (int mt = 0; mt < 4; ++mt)
            for (int r = 0; r < 4; ++r)
                sB[(mt * 16 + q * 4 + r) * P2 + ns + nt * 16 + l15] = (short)f2bf(silu_f(acc[nt][mt][r]));
    __syncthreads();

    // ---- GEMM2: sB @ nW2f + h residual -> out ----
#pragma unroll
    for (int nt = 0; nt < 2; ++nt) {
        float bv = nb2[ns + nt * 16 + l15];
#pragma unroll
        for (int mt = 0; mt < 4; ++mt)
            for (int r = 0; r < 4; ++r) acc[nt][mt][r] = bv;
    }
    for (int kc = 0; kc < 4; ++kc) {
#pragma unroll
        for (int mt = 0; mt < 4; ++mt)
            a[mt] = *(const short8*)&sB[(mt * 16 + l15) * P2 + kc * 32 + q * 8];
#pragma unroll
        for (int nt = 0; nt < 2; ++nt)
            b[nt] = *(const short8*)&nW2f[(((w * 2 + nt) * 4 + kc) * 64 + lane) * 8];
#pragma unroll
        for (int nt = 0; nt < 2; ++nt)
#pragma unroll
            for (int mt = 0; mt < 4; ++mt)
                acc[nt][mt] = __builtin_amdgcn_mfma_f32_16x16x32_bf16(a[mt], b[nt], acc[nt][mt], 0, 0, 0);
    }
#pragma unroll
    for (int nt = 0; nt < 2; ++nt)
#pragma unroll
        for (int mt = 0; mt < 4; ++mt)
            for (int r = 0; r < 4; ++r) {
                int m  = mt * 16 + q * 4 + r;
                int nd = n0 + m;
                if (nd < NNODE) {
                    int n = ns + nt * 16 + l15;
                    out[(long)nd * HID + n] = h[(long)nd * HID + n] + acc[nt][mt][r];
                }
            }
}

// ------------------------------------------------------------------ launch
extern "C" void kernel_launch(void* const* d_in, const int* in_sizes, int n_in,
                              void* d_out, int out_size, void* d_ws, size_t ws_size,
                              hipStream_t stream)
{
    const float* h    = (const float*)d_in[0];
    const float* pos  = (const float*)d_in[1];
    const float* ea   = (const float*)d_in[2];
    const int*   eidx = (const int*)d_in[3];
    const float* eW1  = (const float*)d_in[4];
    const float* eb1  = (const float*)d_in[5];
    const float* eW2  = (const float*)d_in[6];
    const float* eb2  = (const float*)d_in[7];
    const float* nW1  = (const float*)d_in[8];
    const float* nb1  = (const float*)d_in[9];
    const float* nW2  = (const float*)d_in[10];
    const float* nb2  = (const float*)d_in[11];
    const float* cW1  = (const float*)d_in[12];
    const float* cb1  = (const float*)d_in[13];
    const float* cW2  = (const float*)d_in[14];
    const float* cb2  = (const float*)d_in[15];

    float* out    = (float*)d_out;
    float* outpos = out + (long)NNODE * HID;

    char* ws = (char*)d_ws;
    short* wsw    = (short*)ws;
    short* hbf    = (short*)(ws + WS_HBF);
    int*   deg    = (int*)(ws + WS_DEG);
    int*   rowptr = (int*)(ws + WS_ROW);
    int*   cursor = (int*)(ws + WS_CUR);
    int*   bsum   = (int*)(ws + WS_BSUM);
    int*   perm   = (int*)(ws + WS_PERM);

    const short* eW1f = wsw;
    const short* eW2f = wsw + 4608 * 8;
    const short* cW1f = wsw + 6656 * 8;
    const short* nW1f = wsw + 8704 * 8;
    const short* nW2f = wsw + 14848 * 8;

    egnn_prep<<<(16896 + 800000 + NNODE + 255) / 256, 256, 0, stream>>>(
        eW1, eW2, cW1, nW1, nW2, h, wsw, hbf, deg);
    egnn_hist<<<(NEDGE + 255) / 256, 256, 0, stream>>>(eidx, deg);
    egnn_scan1<<<196, 256, 0, stream>>>(deg, rowptr, bsum);
    egnn_scan2<<<1, 256, 0, stream>>>(bsum);
    egnn_scan3<<<196, 256, 0, stream>>>(rowptr, bsum, cursor);
    egnn_scatter<<<(NEDGE + 255) / 256, 256, 0, stream>>>(eidx, cursor, perm);
    egnn_init<<<(NNODE * HID + 255) / 256, 256, 0, stream>>>(pos, out);
    egnn_edge<<<NEDGE / EB, 256, 0, stream>>>(hbf, pos, ea, eidx, perm,
                                              eb1, eb2, cb1, cW2, cb2,
                                              eW1f, eW2f, cW1f, out, outpos);
    egnn_node<<<(NNODE + EB - 1) / EB, 256, 0, stream>>>(h, hbf, out, nb1, nb2,
                                                         nW1f, nW2f, out);
}

// Round 4
// 595.461 us; speedup vs baseline: 1.1876x; 1.1876x over previous
//
#include <hip/hip_runtime.h>
#include <math.h>

#define HID   128
#define NNODE 50000
#define NEDGE 800000
#define EB    64
#define PX    136   // edge buffer pitch (shorts); 68 dwords for fp32 dump reuse
#define P2    152   // node bf16 activation pitch (shorts)
#define PN    392   // node featA pitch (shorts): [h | agg_hi | agg_lo]

typedef __attribute__((ext_vector_type(8))) short short8;
typedef __attribute__((ext_vector_type(4))) float f32x4;

// fast silu: v_rcp instead of IEEE divide (saves ~20 cyc/value at wave64)
__device__ __forceinline__ float silu_f(float x) {
    return x * __builtin_amdgcn_rcpf(1.0f + __expf(-x));
}

__device__ __forceinline__ unsigned short f2bf(float f) {      // RNE
    unsigned int u = __float_as_uint(f);
    u += 0x7FFFu + ((u >> 16) & 1u);
    return (unsigned short)(u >> 16);
}
__device__ __forceinline__ float bf2f(unsigned short s) {
    return __uint_as_float(((unsigned int)s) << 16);
}

// ws layout (bytes)
#define WS_HBF  270336
#define WS_DEG  13070336
#define WS_ROW  13270336
#define WS_CUR  13470336
#define WS_BSUM 13670336
#define WS_PERM 13671360

// ------------------------------------------------------------------ prep: weights->bf16 frags, h->bf16,
//                       zero agg (out h-region), copy pos->outpos, zero deg
__global__ void egnn_prep(const float* eW1, const float* eW2, const float* cW1,
                          const float* nW1, const float* nW2, const float* h,
                          const float* pos,
                          short* wsw, short* hbf, int* deg, float* out)
{
    int g = blockIdx.x * 256 + threadIdx.x;
    if (g < 16896) {
        const float* src; short* dst; int u, Kr, KC, isN1 = 0;
        if (g < 4608)       { src = eW1; dst = wsw;            u = g;         Kr = 258; KC = 9; }
        else if (g < 6656)  { src = eW2; dst = wsw + 4608*8;   u = g - 4608;  Kr = 128; KC = 4; }
        else if (g < 8704)  { src = cW1; dst = wsw + 6656*8;   u = g - 6656;  Kr = 128; KC = 4; }
        else if (g < 14848) { src = nW1; dst = wsw + 8704*8;   u = g - 8704;  Kr = 384; KC = 12; isN1 = 1; }
        else                { src = nW2; dst = wsw + 14848*8;  u = g - 14848; Kr = 128; KC = 4; }
        int nt   = u / (KC * 64);
        int rem  = u % (KC * 64);
        int kc   = rem >> 6;
        int lane = rem & 63;
        int n    = nt * 16 + (lane & 15);
        int kb   = kc * 32 + ((lane >> 4) & 3) * 8;
        short8 o;
#pragma unroll
        for (int j = 0; j < 8; ++j) {
            int k = kb + j;
            int ks = (isN1 && k >= 256) ? (k - 128) : k;
            float v = (k < Kr) ? src[(long)ks * HID + n] : 0.0f;
            o[j] = (short)f2bf(v);
        }
        *(short8*)&dst[(long)u * 8] = o;
    } else if (g < 816896) {                       // h -> bf16 (8 floats/thread)
        long i = (long)(g - 16896) * 8;
        const float4 v0 = *(const float4*)&h[i];
        const float4 v1 = *(const float4*)&h[i + 4];
        short8 o;
        o[0] = (short)f2bf(v0.x); o[1] = (short)f2bf(v0.y);
        o[2] = (short)f2bf(v0.z); o[3] = (short)f2bf(v0.w);
        o[4] = (short)f2bf(v1.x); o[5] = (short)f2bf(v1.y);
        o[6] = (short)f2bf(v1.z); o[7] = (short)f2bf(v1.w);
        *(short8*)&hbf[i] = o;
    } else if (g < 2416896) {                      // zero agg region (float4)
        long i = (long)(g - 816896);
        ((float4*)out)[i] = make_float4(0.f, 0.f, 0.f, 0.f);
    } else if (g < 2566896) {                      // pos -> outpos
        int i = g - 2416896;
        out[(long)NNODE * HID + i] = pos[i];
    } else if (g < 2616896) {                      // zero deg
        int i = g - 2566896;
        deg[i] = 0;
    }
}

// ------------------------------------------------------------------ CSR build
__global__ void egnn_hist(const int* eidx, int* deg)
{
    int i = blockIdx.x * 256 + threadIdx.x;
    if (i < NEDGE / 4) {
        int4 v = ((const int4*)eidx)[i];
        atomicAdd(&deg[v.x], 1); atomicAdd(&deg[v.y], 1);
        atomicAdd(&deg[v.z], 1); atomicAdd(&deg[v.w], 1);
    }
}
__global__ void egnn_scan1(const int* deg, int* rowptr, int* bsum)
{
    __shared__ int s[256];
    int t = threadIdx.x, i = blockIdx.x * 256 + t;
    int v = (i < NNODE) ? deg[i] : 0;
    s[t] = v; __syncthreads();
    for (int o = 1; o < 256; o <<= 1) {
        int x = (t >= o) ? s[t - o] : 0;
        __syncthreads(); s[t] += x; __syncthreads();
    }
    if (i < NNODE) rowptr[i] = s[t] - v;
    if (t == 255) bsum[blockIdx.x] = s[t];
}
__global__ void egnn_scan2(int* bsum)
{
    __shared__ int s[256];
    int t = threadIdx.x;
    int v = (t < 196) ? bsum[t] : 0;
    s[t] = v; __syncthreads();
    for (int o = 1; o < 256; o <<= 1) {
        int x = (t >= o) ? s[t - o] : 0;
        __syncthreads(); s[t] += x; __syncthreads();
    }
    if (t < 196) bsum[t] = s[t] - v;
}
__global__ void egnn_scan3(int* rowptr, const int* bsum, int* cursor)
{
    int i = blockIdx.x * 256 + threadIdx.x;
    if (i < NNODE) {
        int r = rowptr[i] + bsum[blockIdx.x];
        rowptr[i] = r; cursor[i] = r;
    }
}
__global__ void egnn_scatter(const int* eidx, int* cursor, int* perm)
{
    int e = blockIdx.x * 256 + threadIdx.x;
    if (e < NEDGE) {
        int p = atomicAdd(&cursor[eidx[e]], 1);
        perm[p] = e;
    }
}

// ------------------------------------------------------------------ edge phase
// LDS 37.6KB -> 4 blocks/CU. GEMM1 staged in two k-halves; kc=8 frag built in regs.
__global__ __launch_bounds__(256, 4)
void egnn_edge(const short* hbf, const float* pos, const float* ea, const int* eidx,
               const int* perm,
               const float* eb1, const float* eb2, const float* cb1,
               const float* cW2, const float* cb2,
               const short* eW1f, const short* eW2f, const short* cW1f,
               float* aggout, float* outpos)
{
    __shared__ __align__(16) short sX[EB * PX];   // h_row -> h_col -> bf16 m -> fp32 m cols 0-63
    __shared__ __align__(16) short sB[EB * PX];   // silu(L1) -> fp32 m cols 64-127
    __shared__ int   rci[2 * EB];
    __shared__ float rad[EB][4];
    __shared__ float ea_s[EB];
    __shared__ float part[EB][4];

    const int t  = threadIdx.x;
    const int e0 = blockIdx.x * EB;

    // P0: indices + geometry (t<64 owns everything, no cross-thread dep)
    if (t < EB) {
        int e = perm[e0 + t];
        int r = eidx[e], c = eidx[NEDGE + e];
        rci[t] = r; rci[EB + t] = c;
        ea_s[t] = ea[e];
        float dx = pos[(long)r * 3 + 0] - pos[(long)c * 3 + 0];
        float dy = pos[(long)r * 3 + 1] - pos[(long)c * 3 + 1];
        float dz = pos[(long)r * 3 + 2] - pos[(long)c * 3 + 2];
        float rn = fmaxf(sqrtf(dx * dx + dy * dy + dz * dz), 1e-8f);
        rad[t][0] = dx; rad[t][1] = dy; rad[t][2] = dz; rad[t][3] = rn;
    }
    __syncthreads();   // B1

    const int lane = t & 63;
    const int w    = t >> 6;
    const int l15  = lane & 15;
    const int q    = lane >> 4;
    const int ns   = w * 32;

    f32x4 acc[2][4];
    short8 a[4], b[2];
    float mreg[2][4][4];

    // P1: stage h[row]
    for (int i = t; i < EB * 16; i += 256) {
        int e = i >> 4, c16 = i & 15;
        *(uint4*)&sX[e * PX + c16 * 8] = *(const uint4*)&hbf[(long)rci[e] * HID + c16 * 8];
    }
    __syncthreads();   // B2

    // P2: GEMM1 kc=0..3 (h_row half)
#pragma unroll
    for (int nt = 0; nt < 2; ++nt) {
        float bv = eb1[ns + nt * 16 + l15];
#pragma unroll
        for (int mt = 0; mt < 4; ++mt)
            for (int r = 0; r < 4; ++r) acc[nt][mt][r] = bv;
    }
    for (int kc = 0; kc < 4; ++kc) {
#pragma unroll
        for (int mt = 0; mt < 4; ++mt)
            a[mt] = *(const short8*)&sX[(mt * 16 + l15) * PX + kc * 32 + q * 8];
#pragma unroll
        for (int nt = 0; nt < 2; ++nt)
            b[nt] = *(const short8*)&eW1f[(((w * 2 + nt) * 9 + kc) * 64 + lane) * 8];
#pragma unroll
        for (int nt = 0; nt < 2; ++nt)
#pragma unroll
            for (int mt = 0; mt < 4; ++mt)
                acc[nt][mt] = __builtin_amdgcn_mfma_f32_16x16x32_bf16(a[mt], b[nt], acc[nt][mt], 0, 0, 0);
    }
    __syncthreads();   // B3

    // P3: stage h[col] over sX
    for (int i = t; i < EB * 16; i += 256) {
        int e = i >> 4, c16 = i & 15;
        *(uint4*)&sX[e * PX + c16 * 8] = *(const uint4*)&hbf[(long)rci[EB + e] * HID + c16 * 8];
    }
    __syncthreads();   // B4

    // P4: GEMM1 kc=4..7 (h_col half) + kc=8 (rn/ea frag in registers) -> silu -> sB
    for (int kc = 4; kc < 8; ++kc) {
#pragma unroll
        for (int mt = 0; mt < 4; ++mt)
            a[mt] = *(const short8*)&sX[(mt * 16 + l15) * PX + (kc - 4) * 32 + q * 8];
#pragma unroll
        for (int nt = 0; nt < 2; ++nt)
            b[nt] = *(const short8*)&eW1f[(((w * 2 + nt) * 9 + kc) * 64 + lane) * 8];
#pragma unroll
        for (int nt = 0; nt < 2; ++nt)
#pragma unroll
            for (int mt = 0; mt < 4; ++mt)
                acc[nt][mt] = __builtin_amdgcn_mfma_f32_16x16x32_bf16(a[mt], b[nt], acc[nt][mt], 0, 0, 0);
    }
    {
#pragma unroll
        for (int mt = 0; mt < 4; ++mt) {
            int row = mt * 16 + l15;
            short8 a8;
#pragma unroll
            for (int j = 0; j < 8; ++j) a8[j] = 0;
            if (q == 0) {
                a8[0] = (short)f2bf(rad[row][3]);
                a8[1] = (short)f2bf(ea_s[row]);
            }
            a[mt] = a8;
        }
#pragma unroll
        for (int nt = 0; nt < 2; ++nt)
            b[nt] = *(const short8*)&eW1f[(((w * 2 + nt) * 9 + 8) * 64 + lane) * 8];
#pragma unroll
        for (int nt = 0; nt < 2; ++nt)
#pragma unroll
            for (int mt = 0; mt < 4; ++mt)
                acc[nt][mt] = __builtin_amdgcn_mfma_f32_16x16x32_bf16(a[mt], b[nt], acc[nt][mt], 0, 0, 0);
    }
#pragma unroll
    for (int nt = 0; nt < 2; ++nt)
#pragma unroll
        for (int mt = 0; mt < 4; ++mt)
            for (int r = 0; r < 4; ++r)
                sB[(mt * 16 + q * 4 + r) * PX + ns + nt * 16 + l15] = (short)f2bf(silu_f(acc[nt][mt][r]));
    __syncthreads();   // B5

    // P5: GEMM2: sB @ eW2f -> silu = m (fp32 in regs, bf16 into sX)
#pragma unroll
    for (int nt = 0; nt < 2; ++nt) {
        float bv = eb2[ns + nt * 16 + l15];
#pragma unroll
        for (int mt = 0; mt < 4; ++mt)
            for (int r = 0; r < 4; ++r) acc[nt][mt][r] = bv;
    }
    for (int kc = 0; kc < 4; ++kc) {
#pragma unroll
        for (int mt = 0; mt < 4; ++mt)
            a[mt] = *(const short8*)&sB[(mt * 16 + l15) * PX + kc * 32 + q * 8];
#pragma unroll
        for (int nt = 0; nt < 2; ++nt)
            b[nt] = *(const short8*)&eW2f[(((w * 2 + nt) * 4 + kc) * 64 + lane) * 8];
#pragma unroll
        for (int nt = 0; nt < 2; ++nt)
#pragma unroll
            for (int mt = 0; mt < 4; ++mt)
                acc[nt][mt] = __builtin_amdgcn_mfma_f32_16x16x32_bf16(a[mt], b[nt], acc[nt][mt], 0, 0, 0);
    }
#pragma unroll
    for (int nt = 0; nt < 2; ++nt)
#pragma unroll
        for (int mt = 0; mt < 4; ++mt)
            for (int r = 0; r < 4; ++r) {
                float v = silu_f(acc[nt][mt][r]);
                mreg[nt][mt][r] = v;
                sX[(mt * 16 + q * 4 + r) * PX + ns + nt * 16 + l15] = (short)f2bf(v);
            }
    __syncthreads();   // B6

    // P6: GEMM3: m @ cW1f -> silu -> dot(cW2) -> part
#pragma unroll
    for (int nt = 0; nt < 2; ++nt) {
        float bv = cb1[ns + nt * 16 + l15];
#pragma unroll
        for (int mt = 0; mt < 4; ++mt)
            for (int r = 0; r < 4; ++r) acc[nt][mt][r] = bv;
    }
    for (int kc = 0; kc < 4; ++kc) {
#pragma unroll
        for (int mt = 0; mt < 4; ++mt)
            a[mt] = *(const short8*)&sX[(mt * 16 + l15) * PX + kc * 32 + q * 8];
#pragma unroll
        for (int nt = 0; nt < 2; ++nt)
            b[nt] = *(const short8*)&cW1f[(((w * 2 + nt) * 4 + kc) * 64 + lane) * 8];
#pragma unroll
        for (int nt = 0; nt < 2; ++nt)
#pragma unroll
            for (int mt = 0; mt < 4; ++mt)
                acc[nt][mt] = __builtin_amdgcn_mfma_f32_16x16x32_bf16(a[mt], b[nt], acc[nt][mt], 0, 0, 0);
    }
    {
        float cw0 = cW2[ns + l15];
        float cw1 = cW2[ns + 16 + l15];
#pragma unroll
        for (int mt = 0; mt < 4; ++mt) {
            float p[4];
            for (int r = 0; r < 4; ++r)
                p[r] = silu_f(acc[0][mt][r]) * cw0 + silu_f(acc[1][mt][r]) * cw1;
            for (int mask = 1; mask < 16; mask <<= 1)
                for (int r = 0; r < 4; ++r) p[r] += __shfl_xor(p[r], mask);
            if (l15 == 0)
                for (int r = 0; r < 4; ++r) part[mt * 16 + q * 4 + r][w] = p[r];
        }
    }
    __syncthreads();   // B7

    // P7: dump fp32 m (waves 0,1 -> sX cols 0-63; waves 2,3 -> sB cols 64-127) + pos atomics
    {
        float* dst = (w < 2) ? (float*)sX : (float*)sB;
        int cb = (w < 2) ? ns : (ns - 64);
#pragma unroll
        for (int nt = 0; nt < 2; ++nt)
#pragma unroll
            for (int mt = 0; mt < 4; ++mt)
                for (int r = 0; r < 4; ++r)
                    dst[(mt * 16 + q * 4 + r) * 68 + cb + nt * 16 + l15] = mreg[nt][mt][r];
    }
    if (t < EB) {
        float cd  = part[t][0] + part[t][1] + part[t][2] + part[t][3] + cb2[0];
        float inv = cd / rad[t][3];
        int r = rci[t];
        atomicAdd(&outpos[(long)r * 3 + 0], inv * rad[t][0]);
        atomicAdd(&outpos[(long)r * 3 + 1], inv * rad[t][1]);
        atomicAdd(&outpos[(long)r * 3 + 2], inv * rad[t][2]);
    }
    __syncthreads();   // B8

    // P8: run-merged agg atomics (rows sorted; 2 threads/col x 32 edges)
    {
        int j = t >> 1, k = t & 1;
        const float* src = (j < 64) ? (const float*)sX : (const float*)sB;
        int cc = j & 63;
        float s = 0.0f;
        int prev = rci[32 * k];
        for (int e = 32 * k; e < 32 * k + 32; ++e) {
            int rr = rci[e];
            if (rr != prev) {
                atomicAdd(&aggout[(long)prev * HID + j], s);
                s = 0.0f; prev = rr;
            }
            s += src[e * 68 + cc];
        }
        atomicAdd(&aggout[(long)prev * HID + j], s);
    }
}

// ------------------------------------------------------------------ node phase (agg aliases out h-region)
__global__ __launch_bounds__(256)
void egnn_node(const float* h, const short* hbf, const float* agg,
               const float* nb1, const float* nb2,
               const short* nW1f, const short* nW2f,
               float* out)
{
    __shared__ __align__(16) short sA[EB * PN];
    __shared__ __align__(16) short sB2[EB * P2];

    const int t  = threadIdx.x;
    const int n0 = blockIdx.x * EB;

    for (int i = t; i < EB * 16; i += 256) {
        int e = i >> 4, uu = i & 15;
        int nd = n0 + e; if (nd >= NNODE) nd = NNODE - 1;
        *(uint4*)&sA[e * PN + uu * 8] = *(const uint4*)&hbf[(long)nd * HID + uu * 8];
    }
    for (int i = t; i < EB * 32; i += 256) {
        int e = i >> 5, uu = i & 31;
        int nd = n0 + e; if (nd >= NNODE) nd = NNODE - 1;
        const float4 v = *(const float4*)&agg[(long)nd * HID + uu * 4];
        unsigned short hx = f2bf(v.x), hy = f2bf(v.y), hz = f2bf(v.z), hw = f2bf(v.w);
        *(uint2*)&sA[e * PN + HID + uu * 4] =
            make_uint2(hx | ((unsigned int)hy << 16), hz | ((unsigned int)hw << 16));
        unsigned int l0 = f2bf(v.x - bf2f(hx)) | ((unsigned int)f2bf(v.y - bf2f(hy)) << 16);
        unsigned int l1 = f2bf(v.z - bf2f(hz)) | ((unsigned int)f2bf(v.w - bf2f(hw)) << 16);
        *(uint2*)&sA[e * PN + 2 * HID + uu * 4] = make_uint2(l0, l1);
    }
    __syncthreads();

    const int lane = t & 63;
    const int w    = t >> 6;
    const int l15  = lane & 15;
    const int q    = lane >> 4;
    const int ns   = w * 32;

    f32x4 acc[2][4];
    short8 a[4], b[2];

#pragma unroll
    for (int nt = 0; nt < 2; ++nt) {
        float bv = nb1[ns + nt * 16 + l15];
#pragma unroll
        for (int mt = 0; mt < 4; ++mt)
            for (int r = 0; r < 4; ++r) acc[nt][mt][r] = bv;
    }
    for (int kc = 0; kc < 12; ++kc) {
#pragma unroll
        for (int mt = 0; mt < 4; ++mt)
            a[mt] = *(const short8*)&sA[(mt * 16 + l15) * PN + kc * 32 + q * 8];
#pragma unroll
        for (int nt = 0; nt < 2; ++nt)
            b[nt] = *(const short8*)&nW1f[(((w * 2 + nt) * 12 + kc) * 64 + lane) * 8];
#pragma unroll
        for (int nt = 0; nt < 2; ++nt)
#pragma unroll
            for (int mt = 0; mt < 4; ++mt)
                acc[nt][mt] = __builtin_amdgcn_mfma_f32_16x16x32_bf16(a[mt], b[nt], acc[nt][mt], 0, 0, 0);
    }
#pragma unroll
    for (int nt = 0; nt < 2; ++nt)
#pragma unroll
        for (int mt = 0; mt < 4; ++mt)
            for (int r = 0; r < 4; ++r)
                sB2[(mt * 16 + q * 4 + r) * P2 + ns + nt * 16 + l15] = (short)f2bf(silu_f(acc[nt][mt][r]));
    __syncthreads();

#pragma unroll
    for (int nt = 0; nt < 2; ++nt) {
        float bv = nb2[ns + nt * 16 + l15];
#pragma unroll
        for (int mt = 0; mt < 4; ++mt)
            for (int r = 0; r < 4; ++r) acc[nt][mt][r] = bv;
    }
    for (int kc = 0; kc < 4; ++kc) {
#pragma unroll
        for (int mt = 0; mt < 4; ++mt)
            a[mt] = *(const short8*)&sB2[(mt * 16 + l15) * P2 + kc * 32 + q * 8];
#pragma unroll
        for (int nt = 0; nt < 2; ++nt)
            b[nt] = *(const short8*)&nW2f[(((w * 2 + nt) * 4 + kc) * 64 + lane) * 8];
#pragma unroll
        for (int nt = 0; nt < 2; ++nt)
#pragma unroll
            for (int mt = 0; mt < 4; ++mt)
                acc[nt][mt] = __builtin_amdgcn_mfma_f32_16x16x32_bf16(a[mt], b[nt], acc[nt][mt], 0, 0, 0);
    }
#pragma unroll
    for (int nt = 0; nt < 2; ++nt)
#pragma unroll
        for (int mt = 0; mt < 4; ++mt)
            for (int r = 0; r < 4; ++r) {
                int m  = mt * 16 + q * 4 + r;
                int nd = n0 + m;
                if (nd < NNODE) {
                    int n = ns + nt * 16 + l15;
                    out[(long)nd * HID + n] = h[(long)nd * HID + n] + acc[nt][mt][r];
                }
            }
}

// ------------------------------------------------------------------ launch
extern "C" void kernel_launch(void* const* d_in, const int* in_sizes, int n_in,
                              void* d_out, int out_size, void* d_ws, size_t ws_size,
                              hipStream_t stream)
{
    const float* h    = (const float*)d_in[0];
    const float* pos  = (const float*)d_in[1];
    const float* ea   = (const float*)d_in[2];
    const int*   eidx = (const int*)d_in[3];
    const float* eW1  = (const float*)d_in[4];
    const float* eb1  = (const float*)d_in[5];
    const float* eW2  = (const float*)d_in[6];
    const float* eb2  = (const float*)d_in[7];
    const float* nW1  = (const float*)d_in[8];
    const float* nb1  = (const float*)d_in[9];
    const float* nW2  = (const float*)d_in[10];
    const float* nb2  = (const float*)d_in[11];
    const float* cW1  = (const float*)d_in[12];
    const float* cb1  = (const float*)d_in[13];
    const float* cW2  = (const float*)d_in[14];
    const float* cb2  = (const float*)d_in[15];

    float* out    = (float*)d_out;
    float* outpos = out + (long)NNODE * HID;

    char* ws = (char*)d_ws;
    short* wsw    = (short*)ws;
    short* hbf    = (short*)(ws + WS_HBF);
    int*   deg    = (int*)(ws + WS_DEG);
    int*   rowptr = (int*)(ws + WS_ROW);
    int*   cursor = (int*)(ws + WS_CUR);
    int*   bsum   = (int*)(ws + WS_BSUM);
    int*   perm   = (int*)(ws + WS_PERM);

    const short* eW1f = wsw;
    const short* eW2f = wsw + 4608 * 8;
    const short* cW1f = wsw + 6656 * 8;
    const short* nW1f = wsw + 8704 * 8;
    const short* nW2f = wsw + 14848 * 8;

    egnn_prep<<<(2616896 + 255) / 256, 256, 0, stream>>>(
        eW1, eW2, cW1, nW1, nW2, h, pos, wsw, hbf, deg, out);
    egnn_hist<<<(NEDGE / 4 + 255) / 256, 256, 0, stream>>>(eidx, deg);
    egnn_scan1<<<196, 256, 0, stream>>>(deg, rowptr, bsum);
    egnn_scan2<<<1, 256, 0, stream>>>(bsum);
    egnn_scan3<<<196, 256, 0, stream>>>(rowptr, bsum, cursor);
    egnn_scatter<<<(NEDGE + 255) / 256, 256, 0, stream>>>(eidx, cursor, perm);
    egnn_edge<<<NEDGE / EB, 256, 0, stream>>>(hbf, pos, ea, eidx, perm,
                                              eb1, eb2, cb1, cW2, cb2,
                                              eW1f, eW2f, cW1f, out, outpos);
    egnn_node<<<(NNODE + EB - 1) / EB, 256, 0, stream>>>(h, hbf, out, nb1, nb2,
                                                         nW1f, nW2f, out);
}

// Round 5
// 586.390 us; speedup vs baseline: 1.2060x; 1.0155x over previous
//
#include <hip/hip_runtime.h>
#include <hip/hip_bf16.h>
#include <math.h>

#define HID   128
#define NNODE 50000
#define NEDGE 800000
#define EB    64
#define PX    136   // edge/intermediate pitch (shorts) = 68 dwords = 34 float2
#define PN    392   // node featA pitch (shorts): [h | agg_hi | agg_lo]

typedef __attribute__((ext_vector_type(8))) short short8;
typedef __attribute__((ext_vector_type(4))) float f32x4;

__device__ __forceinline__ float silu_f(float x) {
    return x * __builtin_amdgcn_rcpf(1.0f + __expf(-x));
}
__device__ __forceinline__ float2 silu2(float x, float y) {
    return make_float2(x * __builtin_amdgcn_rcpf(1.0f + __expf(-x)),
                       y * __builtin_amdgcn_rcpf(1.0f + __expf(-y)));
}
__device__ __forceinline__ unsigned int pkbf(float2 v) {   // packed RNE f32x2 -> bf16x2
    __hip_bfloat162 b2 = __float22bfloat162_rn(v);
    return *(unsigned int*)&b2;
}
__device__ __forceinline__ unsigned short f2bf(float f) {  // scalar RNE
    unsigned int u = __float_as_uint(f);
    u += 0x7FFFu + ((u >> 16) & 1u);
    return (unsigned short)(u >> 16);
}
__device__ __forceinline__ float bf2f(unsigned short s) {
    return __uint_as_float(((unsigned int)s) << 16);
}
// physical col p (in a 128-wide interleaved buffer) -> logical col
__device__ __forceinline__ int permk(int p) {
    return (p & ~31) | ((p & 31) >> 1) | ((p & 1) << 4);
}

// ws layout (bytes)
#define WS_HBF  270336
#define WS_DEG  13070336
#define WS_ROW  13270336
#define WS_CUR  13470336
#define WS_BSUM 13670336
#define WS_PERM 13671360

// ------------------------------------------------------------------ prep
// weights -> bf16 frag-major (with k-permutation for interleaved-buffer consumers),
// h -> bf16, zero agg (out h-region), pos -> outpos, zero deg
__global__ void egnn_prep(const float* eW1, const float* eW2, const float* cW1,
                          const float* nW1, const float* nW2, const float* h,
                          const float* pos,
                          short* wsw, short* hbf, int* deg, float* out)
{
    int g = blockIdx.x * 256 + threadIdx.x;
    if (g < 16896) {
        const float* src; short* dst; int u, Kr, KC, mode;
        if (g < 4608)       { src = eW1; dst = wsw;            u = g;         Kr = 258; KC = 9;  mode = 0; }
        else if (g < 6656)  { src = eW2; dst = wsw + 4608*8;   u = g - 4608;  Kr = 128; KC = 4;  mode = 1; }
        else if (g < 8704)  { src = cW1; dst = wsw + 6656*8;   u = g - 6656;  Kr = 128; KC = 4;  mode = 1; }
        else if (g < 14848) { src = nW1; dst = wsw + 8704*8;   u = g - 8704;  Kr = 384; KC = 12; mode = 2; }
        else                { src = nW2; dst = wsw + 14848*8;  u = g - 14848; Kr = 128; KC = 4;  mode = 1; }
        int nt   = u / (KC * 64);
        int rem  = u % (KC * 64);
        int kc   = rem >> 6;
        int lane = rem & 63;
        int n    = nt * 16 + (lane & 15);
        int kb   = kc * 32 + ((lane >> 4) & 3) * 8;
        short8 o;
#pragma unroll
        for (int j = 0; j < 8; ++j) {
            int k = kb + j;
            int ks;
            if (mode == 0)      ks = k;
            else if (mode == 1) ks = permk(k);
            else {              // nW1: h natural, agg hi/lo permuted (lo reuses same rows)
                if (k < 128)      ks = k;
                else if (k < 256) ks = 128 + permk(k - 128);
                else              ks = 128 + permk(k - 256);
            }
            float v = (k < Kr) ? src[(long)ks * HID + n] : 0.0f;
            o[j] = (short)f2bf(v);
        }
        *(short8*)&dst[(long)u * 8] = o;
    } else if (g < 816896) {                       // h -> bf16
        long i = (long)(g - 16896) * 8;
        const float4 v0 = *(const float4*)&h[i];
        const float4 v1 = *(const float4*)&h[i + 4];
        uint2 lohi;
        lohi.x = pkbf(make_float2(v0.x, v0.y));
        lohi.y = pkbf(make_float2(v0.z, v0.w));
        uint2 hihi;
        hihi.x = pkbf(make_float2(v1.x, v1.y));
        hihi.y = pkbf(make_float2(v1.z, v1.w));
        *(uint4*)&hbf[i] = make_uint4(lohi.x, lohi.y, hihi.x, hihi.y);
    } else if (g < 2416896) {                      // zero agg region
        long i = (long)(g - 816896);
        ((float4*)out)[i] = make_float4(0.f, 0.f, 0.f, 0.f);
    } else if (g < 2566896) {                      // pos -> outpos
        int i = g - 2416896;
        out[(long)NNODE * HID + i] = pos[i];
    } else if (g < 2616896) {                      // zero deg
        int i = g - 2566896;
        deg[i] = 0;
    }
}

// ------------------------------------------------------------------ CSR build
__global__ void egnn_hist(const int* eidx, int* deg)
{
    int i = blockIdx.x * 256 + threadIdx.x;
    if (i < NEDGE / 4) {
        int4 v = ((const int4*)eidx)[i];
        atomicAdd(&deg[v.x], 1); atomicAdd(&deg[v.y], 1);
        atomicAdd(&deg[v.z], 1); atomicAdd(&deg[v.w], 1);
    }
}
__global__ void egnn_scan1(const int* deg, int* rowptr, int* bsum)
{
    __shared__ int s[256];
    int t = threadIdx.x, i = blockIdx.x * 256 + t;
    int v = (i < NNODE) ? deg[i] : 0;
    s[t] = v; __syncthreads();
    for (int o = 1; o < 256; o <<= 1) {
        int x = (t >= o) ? s[t - o] : 0;
        __syncthreads(); s[t] += x; __syncthreads();
    }
    if (i < NNODE) rowptr[i] = s[t] - v;
    if (t == 255) bsum[blockIdx.x] = s[t];
}
__global__ void egnn_scanF(int* rowptr, const int* bsum, int* cursor)
{
    __shared__ int red[256];
    int t = threadIdx.x, b = blockIdx.x;
    int acc = 0;
    for (int i = t; i < b; i += 256) acc += bsum[i];
    red[t] = acc; __syncthreads();
    for (int o = 128; o > 0; o >>= 1) {
        if (t < o) red[t] += red[t + o];
        __syncthreads();
    }
    int i = b * 256 + t;
    if (i < NNODE) {
        int r = rowptr[i] + red[0];
        cursor[i] = r;
    }
}
__global__ void egnn_scatter(const int* eidx, int* cursor, int* perm)
{
    int e = blockIdx.x * 256 + threadIdx.x;
    if (e < NEDGE) {
        int p = atomicAdd(&cursor[eidx[e]], 1);
        perm[p] = e;
    }
}

// ------------------------------------------------------------------ edge phase
__global__ __launch_bounds__(256, 4)
void egnn_edge(const short* hbf, const float* pos, const float* ea, const int* eidx,
               const int* perm,
               const float* eb1, const float* eb2, const float* cb1,
               const float* cW2, const float* cb2,
               const short* eW1f, const short* eW2f, const short* cW1f,
               float* aggout, float* outpos)
{
    __shared__ __align__(16) short sX[EB * PX];   // h_row -> h_col -> bf16 m -> fp32 m (cp 0-31)
    __shared__ __align__(16) short sB[EB * PX];   // silu(L1) -> fp32 m (cp 32-63)
    __shared__ int   rci[2 * EB];
    __shared__ float rad[EB][4];
    __shared__ float ea_s[EB];
    __shared__ float part[EB][4];

    const int t  = threadIdx.x;
    const int e0 = blockIdx.x * EB;
    const int lane = t & 63;
    const int w    = t >> 6;
    const int l15  = lane & 15;
    const int q    = lane >> 4;
    const int ns   = w * 32;

    short8 bb[4][2];   // B-fragment preload (forces loads in flight across MFMA)
    short8 a[4];
    f32x4 acc[2][4];
    float2 mreg2[4][4];

    // preload GEMM1 kc=0..3 B-frags immediately (independent of all LDS)
#pragma unroll
    for (int kc = 0; kc < 4; ++kc)
#pragma unroll
        for (int nt = 0; nt < 2; ++nt)
            bb[kc][nt] = *(const short8*)&eW1f[(((w * 2 + nt) * 9 + kc) * 64 + lane) * 8];

    // P0: indices + geometry
    if (t < EB) {
        int e = perm[e0 + t];
        int r = eidx[e], c = eidx[NEDGE + e];
        rci[t] = r; rci[EB + t] = c;
        ea_s[t] = ea[e];
        float dx = pos[(long)r * 3 + 0] - pos[(long)c * 3 + 0];
        float dy = pos[(long)r * 3 + 1] - pos[(long)c * 3 + 1];
        float dz = pos[(long)r * 3 + 2] - pos[(long)c * 3 + 2];
        float rn = fmaxf(sqrtf(dx * dx + dy * dy + dz * dz), 1e-8f);
        rad[t][0] = dx; rad[t][1] = dy; rad[t][2] = dz; rad[t][3] = rn;
    }
    __syncthreads();   // B1

    // P1: stage h[row]
    for (int i = t; i < EB * 16; i += 256) {
        int e = i >> 4, c16 = i & 15;
        *(uint4*)&sX[e * PX + c16 * 8] = *(const uint4*)&hbf[(long)rci[e] * HID + c16 * 8];
    }
    __syncthreads();   // B2

    // P2: GEMM1 kc=0..3 (h_row half)
#pragma unroll
    for (int nt = 0; nt < 2; ++nt) {
        float bv = eb1[ns + nt * 16 + l15];
#pragma unroll
        for (int mt = 0; mt < 4; ++mt)
            for (int r = 0; r < 4; ++r) acc[nt][mt][r] = bv;
    }
#pragma unroll
    for (int kc = 0; kc < 4; ++kc) {
#pragma unroll
        for (int mt = 0; mt < 4; ++mt)
            a[mt] = *(const short8*)&sX[(mt * 16 + l15) * PX + kc * 32 + q * 8];
#pragma unroll
        for (int nt = 0; nt < 2; ++nt)
#pragma unroll
            for (int mt = 0; mt < 4; ++mt)
                acc[nt][mt] = __builtin_amdgcn_mfma_f32_16x16x32_bf16(a[mt], bb[kc][nt], acc[nt][mt], 0, 0, 0);
    }
    // preload GEMM1 kc=4..7 B-frags
#pragma unroll
    for (int kc = 0; kc < 4; ++kc)
#pragma unroll
        for (int nt = 0; nt < 2; ++nt)
            bb[kc][nt] = *(const short8*)&eW1f[(((w * 2 + nt) * 9 + kc + 4) * 64 + lane) * 8];
    __syncthreads();   // B3

    // P3: stage h[col] over sX
    for (int i = t; i < EB * 16; i += 256) {
        int e = i >> 4, c16 = i & 15;
        *(uint4*)&sX[e * PX + c16 * 8] = *(const uint4*)&hbf[(long)rci[EB + e] * HID + c16 * 8];
    }
    __syncthreads();   // B4

    // P4: GEMM1 kc=4..7 (h_col half) + kc=8 (rn/ea in regs) -> silu -> sB (interleaved)
#pragma unroll
    for (int kc = 0; kc < 4; ++kc) {
#pragma unroll
        for (int mt = 0; mt < 4; ++mt)
            a[mt] = *(const short8*)&sX[(mt * 16 + l15) * PX + kc * 32 + q * 8];
#pragma unroll
        for (int nt = 0; nt < 2; ++nt)
#pragma unroll
            for (int mt = 0; mt < 4; ++mt)
                acc[nt][mt] = __builtin_amdgcn_mfma_f32_16x16x32_bf16(a[mt], bb[kc][nt], acc[nt][mt], 0, 0, 0);
    }
    {
        short8 b8[2];
#pragma unroll
        for (int nt = 0; nt < 2; ++nt)
            b8[nt] = *(const short8*)&eW1f[(((w * 2 + nt) * 9 + 8) * 64 + lane) * 8];
#pragma unroll
        for (int mt = 0; mt < 4; ++mt) {
            int row = mt * 16 + l15;
            short8 a8;
#pragma unroll
            for (int j = 0; j < 8; ++j) a8[j] = 0;
            if (q == 0) {
                a8[0] = (short)f2bf(rad[row][3]);
                a8[1] = (short)f2bf(ea_s[row]);
            }
            a[mt] = a8;
        }
#pragma unroll
        for (int nt = 0; nt < 2; ++nt)
#pragma unroll
            for (int mt = 0; mt < 4; ++mt)
                acc[nt][mt] = __builtin_amdgcn_mfma_f32_16x16x32_bf16(a[mt], b8[nt], acc[nt][mt], 0, 0, 0);
    }
    // preload GEMM2 B-frags
#pragma unroll
    for (int kc = 0; kc < 4; ++kc)
#pragma unroll
        for (int nt = 0; nt < 2; ++nt)
            bb[kc][nt] = *(const short8*)&eW2f[(((w * 2 + nt) * 4 + kc) * 64 + lane) * 8];
#pragma unroll
    for (int mt = 0; mt < 4; ++mt)
#pragma unroll
        for (int r = 0; r < 4; ++r) {
            float2 v = silu2(acc[0][mt][r], acc[1][mt][r]);
            *(unsigned int*)&sB[(mt * 16 + q * 4 + r) * PX + ns + 2 * l15] = pkbf(v);
        }
    __syncthreads();   // B5

    // P5: GEMM2: sB @ eW2f -> silu = m (float2 regs + interleaved bf16 into sX)
#pragma unroll
    for (int nt = 0; nt < 2; ++nt) {
        float bv = eb2[ns + nt * 16 + l15];
#pragma unroll
        for (int mt = 0; mt < 4; ++mt)
            for (int r = 0; r < 4; ++r) acc[nt][mt][r] = bv;
    }
#pragma unroll
    for (int kc = 0; kc < 4; ++kc) {
#pragma unroll
        for (int mt = 0; mt < 4; ++mt)
            a[mt] = *(const short8*)&sB[(mt * 16 + l15) * PX + kc * 32 + q * 8];
#pragma unroll
        for (int nt = 0; nt < 2; ++nt)
#pragma unroll
            for (int mt = 0; mt < 4; ++mt)
                acc[nt][mt] = __builtin_amdgcn_mfma_f32_16x16x32_bf16(a[mt], bb[kc][nt], acc[nt][mt], 0, 0, 0);
    }
    // preload GEMM3 B-frags
#pragma unroll
    for (int kc = 0; kc < 4; ++kc)
#pragma unroll
        for (int nt = 0; nt < 2; ++nt)
            bb[kc][nt] = *(const short8*)&cW1f[(((w * 2 + nt) * 4 + kc) * 64 + lane) * 8];
#pragma unroll
    for (int mt = 0; mt < 4; ++mt)
#pragma unroll
        for (int r = 0; r < 4; ++r) {
            float2 v = silu2(acc[0][mt][r], acc[1][mt][r]);
            mreg2[mt][r] = v;
            *(unsigned int*)&sX[(mt * 16 + q * 4 + r) * PX + ns + 2 * l15] = pkbf(v);
        }
    __syncthreads();   // B6

    // P6: GEMM3: m @ cW1f -> silu -> dot(cW2) -> part
#pragma unroll
    for (int nt = 0; nt < 2; ++nt) {
        float bv = cb1[ns + nt * 16 + l15];
#pragma unroll
        for (int mt = 0; mt < 4; ++mt)
            for (int r = 0; r < 4; ++r) acc[nt][mt][r] = bv;
    }
#pragma unroll
    for (int kc = 0; kc < 4; ++kc) {
#pragma unroll
        for (int mt = 0; mt < 4; ++mt)
            a[mt] = *(const short8*)&sX[(mt * 16 + l15) * PX + kc * 32 + q * 8];
#pragma unroll
        for (int nt = 0; nt < 2; ++nt)
#pragma unroll
            for (int mt = 0; mt < 4; ++mt)
                acc[nt][mt] = __builtin_amdgcn_mfma_f32_16x16x32_bf16(a[mt], bb[kc][nt], acc[nt][mt], 0, 0, 0);
    }
    {
        float cw0 = cW2[ns + l15];
        float cw1 = cW2[ns + 16 + l15];
#pragma unroll
        for (int mt = 0; mt < 4; ++mt) {
            float p[4];
            for (int r = 0; r < 4; ++r) {
                float2 s = silu2(acc[0][mt][r], acc[1][mt][r]);
                p[r] = s.x * cw0 + s.y * cw1;
            }
            for (int mask = 1; mask < 16; mask <<= 1)
                for (int r = 0; r < 4; ++r) p[r] += __shfl_xor(p[r], mask);
            if (l15 == 0)
                for (int r = 0; r < 4; ++r) part[mt * 16 + q * 4 + r][w] = p[r];
        }
    }
    __syncthreads();   // B7

    // P7: fp32 m dump as float2 (waves 0,1 -> sX, waves 2,3 -> sB) + pos atomics
    {
        float2* dst = (w < 2) ? (float2*)sX : (float2*)sB;
        int cp = w * 16 + l15 - ((w < 2) ? 0 : 32);
#pragma unroll
        for (int mt = 0; mt < 4; ++mt)
#pragma unroll
            for (int r = 0; r < 4; ++r)
                dst[(mt * 16 + q * 4 + r) * 34 + cp] = mreg2[mt][r];
    }
    if (t < EB) {
        float cd  = part[t][0] + part[t][1] + part[t][2] + part[t][3] + cb2[0];
        float inv = cd / rad[t][3];
        int r = rci[t];
        atomicAdd(&outpos[(long)r * 3 + 0], inv * rad[t][0]);
        atomicAdd(&outpos[(long)r * 3 + 1], inv * rad[t][1]);
        atomicAdd(&outpos[(long)r * 3 + 2], inv * rad[t][2]);
    }
    __syncthreads();   // B8

    // P8: run-merged agg atomics (physical col order; adjacent-pair atomics)
    {
        int q4 = t >> 6, cp = t & 63;               // col-pair cp, edge quarter q4
        const float2* srcf = (cp < 32) ? (const float2*)sX : (const float2*)sB;
        int cc = cp & 31;
        int p0 = 2 * cp;                            // physical cols p0, p0+1
        int ei = q4 * 16;
        float sx = 0.f, sy = 0.f;
        int prev = rci[ei];
        for (int e = ei; e < ei + 16; ++e) {
            int rr = rci[e];
            if (rr != prev) {
                atomicAdd(&aggout[(long)prev * HID + p0], sx);
                atomicAdd(&aggout[(long)prev * HID + p0 + 1], sy);
                sx = sy = 0.f; prev = rr;
            }
            float2 v = srcf[e * 34 + cc];
            sx += v.x; sy += v.y;
        }
        atomicAdd(&aggout[(long)prev * HID + p0], sx);
        atomicAdd(&aggout[(long)prev * HID + p0 + 1], sy);
    }
}

// ------------------------------------------------------------------ node phase (agg aliases out h-region)
__global__ __launch_bounds__(256)
void egnn_node(const float* h, const short* hbf, const float* agg,
               const float* nb1, const float* nb2,
               const short* nW1f, const short* nW2f,
               float* out)
{
    __shared__ __align__(16) short sA[EB * PN];
    __shared__ __align__(16) short sB2[EB * PX];

    const int t  = threadIdx.x;
    const int n0 = blockIdx.x * EB;

    for (int i = t; i < EB * 16; i += 256) {
        int e = i >> 4, uu = i & 15;
        int nd = n0 + e; if (nd >= NNODE) nd = NNODE - 1;
        *(uint4*)&sA[e * PN + uu * 8] = *(const uint4*)&hbf[(long)nd * HID + uu * 8];
    }
    for (int i = t; i < EB * 32; i += 256) {
        int e = i >> 5, uu = i & 31;
        int nd = n0 + e; if (nd >= NNODE) nd = NNODE - 1;
        const float4 v = *(const float4*)&agg[(long)nd * HID + uu * 4];
        unsigned short hx = f2bf(v.x), hy = f2bf(v.y), hz = f2bf(v.z), hw = f2bf(v.w);
        *(uint2*)&sA[e * PN + HID + uu * 4] =
            make_uint2(hx | ((unsigned int)hy << 16), hz | ((unsigned int)hw << 16));
        unsigned int l0 = pkbf(make_float2(v.x - bf2f(hx), v.y - bf2f(hy)));
        unsigned int l1 = pkbf(make_float2(v.z - bf2f(hz), v.w - bf2f(hw)));
        *(uint2*)&sA[e * PN + 2 * HID + uu * 4] = make_uint2(l0, l1);
    }
    __syncthreads();

    const int lane = t & 63;
    const int w    = t >> 6;
    const int l15  = lane & 15;
    const int q    = lane >> 4;
    const int ns   = w * 32;

    f32x4 acc[2][4];
    short8 a[4], b[2];

#pragma unroll
    for (int nt = 0; nt < 2; ++nt) {
        float bv = nb1[ns + nt * 16 + l15];
#pragma unroll
        for (int mt = 0; mt < 4; ++mt)
            for (int r = 0; r < 4; ++r) acc[nt][mt][r] = bv;
    }
    for (int kc = 0; kc < 12; ++kc) {
#pragma unroll
        for (int mt = 0; mt < 4; ++mt)
            a[mt] = *(const short8*)&sA[(mt * 16 + l15) * PN + kc * 32 + q * 8];
#pragma unroll
        for (int nt = 0; nt < 2; ++nt)
            b[nt] = *(const short8*)&nW1f[(((w * 2 + nt) * 12 + kc) * 64 + lane) * 8];
#pragma unroll
        for (int nt = 0; nt < 2; ++nt)
#pragma unroll
            for (int mt = 0; mt < 4; ++mt)
                acc[nt][mt] = __builtin_amdgcn_mfma_f32_16x16x32_bf16(a[mt], b[nt], acc[nt][mt], 0, 0, 0);
    }
#pragma unroll
    for (int mt = 0; mt < 4; ++mt)
#pragma unroll
        for (int r = 0; r < 4; ++r) {
            float2 v = silu2(acc[0][mt][r], acc[1][mt][r]);
            *(unsigned int*)&sB2[(mt * 16 + q * 4 + r) * PX + ns + 2 * l15] = pkbf(v);
        }
    __syncthreads();

#pragma unroll
    for (int nt = 0; nt < 2; ++nt) {
        float bv = nb2[ns + nt * 16 + l15];
#pragma unroll
        for (int mt = 0; mt < 4; ++mt)
            for (int r = 0; r < 4; ++r) acc[nt][mt][r] = bv;
    }
    for (int kc = 0; kc < 4; ++kc) {
#pragma unroll
        for (int mt = 0; mt < 4; ++mt)
            a[mt] = *(const short8*)&sB2[(mt * 16 + l15) * PX + kc * 32 + q * 8];
#pragma unroll
        for (int nt = 0; nt < 2; ++nt)
            b[nt] = *(const short8*)&nW2f[(((w * 2 + nt) * 4 + kc) * 64 + lane) * 8];
#pragma unroll
        for (int nt = 0; nt < 2; ++nt)
#pragma unroll
            for (int mt = 0; mt < 4; ++mt)
                acc[nt][mt] = __builtin_amdgcn_mfma_f32_16x16x32_bf16(a[mt], b[nt], acc[nt][mt], 0, 0, 0);
    }
#pragma unroll
    for (int nt = 0; nt < 2; ++nt)
#pragma unroll
        for (int mt = 0; mt < 4; ++mt)
            for (int r = 0; r < 4; ++r) {
                int m  = mt * 16 + q * 4 + r;
                int nd = n0 + m;
                if (nd < NNODE) {
                    int n = ns + nt * 16 + l15;
                    out[(long)nd * HID + n] = h[(long)nd * HID + n] + acc[nt][mt][r];
                }
            }
}

// ------------------------------------------------------------------ launch
extern "C" void kernel_launch(void* const* d_in, const int* in_sizes, int n_in,
                              void* d_out, int out_size, void* d_ws, size_t ws_size,
                              hipStream_t stream)
{
    const float* h    = (const float*)d_in[0];
    const float* pos  = (const float*)d_in[1];
    const float* ea   = (const float*)d_in[2];
    const int*   eidx = (const int*)d_in[3];
    const float* eW1  = (const float*)d_in[4];
    const float* eb1  = (const float*)d_in[5];
    const float* eW2  = (const float*)d_in[6];
    const float* eb2  = (const float*)d_in[7];
    const float* nW1  = (const float*)d_in[8];
    const float* nb1  = (const float*)d_in[9];
    const float* nW2  = (const float*)d_in[10];
    const float* nb2  = (const float*)d_in[11];
    const float* cW1  = (const float*)d_in[12];
    const float* cb1  = (const float*)d_in[13];
    const float* cW2  = (const float*)d_in[14];
    const float* cb2  = (const float*)d_in[15];

    float* out    = (float*)d_out;
    float* outpos = out + (long)NNODE * HID;

    char* ws = (char*)d_ws;
    short* wsw    = (short*)ws;
    short* hbf    = (short*)(ws + WS_HBF);
    int*   deg    = (int*)(ws + WS_DEG);
    int*   rowptr = (int*)(ws + WS_ROW);
    int*   cursor = (int*)(ws + WS_CUR);
    int*   bsum   = (int*)(ws + WS_BSUM);
    int*   perm   = (int*)(ws + WS_PERM);

    const short* eW1f = wsw;
    const short* eW2f = wsw + 4608 * 8;
    const short* cW1f = wsw + 6656 * 8;
    const short* nW1f = wsw + 8704 * 8;
    const short* nW2f = wsw + 14848 * 8;

    egnn_prep<<<(2616896 + 255) / 256, 256, 0, stream>>>(
        eW1, eW2, cW1, nW1, nW2, h, pos, wsw, hbf, deg, out);
    egnn_hist<<<(NEDGE / 4 + 255) / 256, 256, 0, stream>>>(eidx, deg);
    egnn_scan1<<<196, 256, 0, stream>>>(deg, rowptr, bsum);
    egnn_scanF<<<196, 256, 0, stream>>>(rowptr, bsum, cursor);
    egnn_scatter<<<(NEDGE + 255) / 256, 256, 0, stream>>>(eidx, cursor, perm);
    egnn_edge<<<NEDGE / EB, 256, 0, stream>>>(hbf, pos, ea, eidx, perm,
                                              eb1, eb2, cb1, cW2, cb2,
                                              eW1f, eW2f, cW1f, out, outpos);
    egnn_node<<<(NNODE + EB - 1) / EB, 256, 0, stream>>>(h, hbf, out, nb1, nb2,
                                                         nW1f, nW2f, out);
}

// Round 6
// 542.537 us; speedup vs baseline: 1.3035x; 1.0808x over previous
//
#include <hip/hip_runtime.h>
#include <hip/hip_bf16.h>
#include <math.h>

#define HID   128
#define NNODE 50000
#define NEDGE 800000
#define EB    64
#define PX    136   // edge/intermediate pitch (shorts) = 68 dwords = 34 float2
#define PN    392   // node featA pitch (shorts): [h | agg_hi | agg_lo]

typedef __attribute__((ext_vector_type(8))) short short8;
typedef __attribute__((ext_vector_type(4))) float f32x4;

__device__ __forceinline__ float2 silu2(float x, float y) {
    return make_float2(x * __builtin_amdgcn_rcpf(1.0f + __expf(-x)),
                       y * __builtin_amdgcn_rcpf(1.0f + __expf(-y)));
}
__device__ __forceinline__ unsigned int pkbf(float2 v) {   // packed RNE f32x2 -> bf16x2
    __hip_bfloat162 b2 = __float22bfloat162_rn(v);
    return *(unsigned int*)&b2;
}
__device__ __forceinline__ unsigned short f2bf(float f) {  // scalar RNE
    unsigned int u = __float_as_uint(f);
    u += 0x7FFFu + ((u >> 16) & 1u);
    return (unsigned short)(u >> 16);
}
__device__ __forceinline__ float bf2f(unsigned short s) {
    return __uint_as_float(((unsigned int)s) << 16);
}
// physical col p (in a 128-wide interleaved buffer) -> logical col
__device__ __forceinline__ int permk(int p) {
    return (p & ~31) | ((p & 31) >> 1) | ((p & 1) << 4);
}

// ws layout (bytes)
#define WS_HBF  270336
#define WS_DEG  13070336
#define WS_ROW  13270336
#define WS_CUR  13470336
#define WS_BSUM 13670336
#define WS_PERM 13671360

// ------------------------------------------------------------------ prep
__global__ void egnn_prep(const float* eW1, const float* eW2, const float* cW1,
                          const float* nW1, const float* nW2, const float* h,
                          const float* pos,
                          short* wsw, short* hbf, int* deg, float* out)
{
    int g = blockIdx.x * 256 + threadIdx.x;
    if (g < 16896) {
        const float* src; short* dst; int u, Kr, KC, mode;
        if (g < 4608)       { src = eW1; dst = wsw;            u = g;         Kr = 258; KC = 9;  mode = 0; }
        else if (g < 6656)  { src = eW2; dst = wsw + 4608*8;   u = g - 4608;  Kr = 128; KC = 4;  mode = 1; }
        else if (g < 8704)  { src = cW1; dst = wsw + 6656*8;   u = g - 6656;  Kr = 128; KC = 4;  mode = 1; }
        else if (g < 14848) { src = nW1; dst = wsw + 8704*8;   u = g - 8704;  Kr = 384; KC = 12; mode = 2; }
        else                { src = nW2; dst = wsw + 14848*8;  u = g - 14848; Kr = 128; KC = 4;  mode = 1; }
        int nt   = u / (KC * 64);
        int rem  = u % (KC * 64);
        int kc   = rem >> 6;
        int lane = rem & 63;
        int n    = nt * 16 + (lane & 15);
        int kb   = kc * 32 + ((lane >> 4) & 3) * 8;
        short8 o;
#pragma unroll
        for (int j = 0; j < 8; ++j) {
            int k = kb + j;
            int ks;
            if (mode == 0)      ks = k;
            else if (mode == 1) ks = permk(k);
            else {              // nW1: h natural, agg hi/lo permuted (lo reuses same rows)
                if (k < 128)      ks = k;
                else if (k < 256) ks = 128 + permk(k - 128);
                else              ks = 128 + permk(k - 256);
            }
            float v = (k < Kr) ? src[(long)ks * HID + n] : 0.0f;
            o[j] = (short)f2bf(v);
        }
        *(short8*)&dst[(long)u * 8] = o;
    } else if (g < 816896) {                       // h -> bf16
        long i = (long)(g - 16896) * 8;
        const float4 v0 = *(const float4*)&h[i];
        const float4 v1 = *(const float4*)&h[i + 4];
        uint4 o;
        o.x = pkbf(make_float2(v0.x, v0.y));
        o.y = pkbf(make_float2(v0.z, v0.w));
        o.z = pkbf(make_float2(v1.x, v1.y));
        o.w = pkbf(make_float2(v1.z, v1.w));
        *(uint4*)&hbf[i] = o;
    } else if (g < 2416896) {                      // zero agg region
        long i = (long)(g - 816896);
        ((float4*)out)[i] = make_float4(0.f, 0.f, 0.f, 0.f);
    } else if (g < 2566896) {                      // pos -> outpos
        int i = g - 2416896;
        out[(long)NNODE * HID + i] = pos[i];
    } else if (g < 2616896) {                      // zero deg
        int i = g - 2566896;
        deg[i] = 0;
    }
}

// ------------------------------------------------------------------ CSR build
__global__ void egnn_hist(const int* eidx, int* deg)
{
    int i = blockIdx.x * 256 + threadIdx.x;
    if (i < NEDGE / 4) {
        int4 v = ((const int4*)eidx)[i];
        atomicAdd(&deg[v.x], 1); atomicAdd(&deg[v.y], 1);
        atomicAdd(&deg[v.z], 1); atomicAdd(&deg[v.w], 1);
    }
}
__global__ void egnn_scan1(const int* deg, int* rowptr, int* bsum)
{
    __shared__ int s[256];
    int t = threadIdx.x, i = blockIdx.x * 256 + t;
    int v = (i < NNODE) ? deg[i] : 0;
    s[t] = v; __syncthreads();
    for (int o = 1; o < 256; o <<= 1) {
        int x = (t >= o) ? s[t - o] : 0;
        __syncthreads(); s[t] += x; __syncthreads();
    }
    if (i < NNODE) rowptr[i] = s[t] - v;
    if (t == 255) bsum[blockIdx.x] = s[t];
}
__global__ void egnn_scanF(int* rowptr, const int* bsum, int* cursor)
{
    __shared__ int red[256];
    int t = threadIdx.x, b = blockIdx.x;
    int acc = 0;
    for (int i = t; i < b; i += 256) acc += bsum[i];
    red[t] = acc; __syncthreads();
    for (int o = 128; o > 0; o >>= 1) {
        if (t < o) red[t] += red[t + o];
        __syncthreads();
    }
    int i = b * 256 + t;
    if (i < NNODE) cursor[i] = rowptr[i] + red[0];
}
__global__ void egnn_scatter(const int* eidx, int* cursor, int* perm)
{
    int e = blockIdx.x * 256 + threadIdx.x;
    if (e < NEDGE) {
        int p = atomicAdd(&cursor[eidx[e]], 1);
        perm[p] = e;
    }
}

// ------------------------------------------------------------------ edge phase (6 barriers)
__global__ __launch_bounds__(256, 4)
void egnn_edge(const short* hbf, const float* pos, const float* ea, const int* eidx,
               const int* perm,
               const float* eb1, const float* eb2, const float* cb1,
               const float* cW2, const float* cb2,
               const short* eW1f, const short* eW2f, const short* cW1f,
               float* aggout, float* outpos)
{
    __shared__ __align__(16) short sX[EB * PX];   // h_row -> bf16 m -> fp32 m (cols 0-63)
    __shared__ __align__(16) short sB[EB * PX];   // h_col -> silu(L1) -> fp32 m (cols 64-127)
    __shared__ int   rci[2 * EB];
    __shared__ float rad[EB][4];
    __shared__ float ea_s[EB];
    __shared__ float part[EB][4];

    const int t  = threadIdx.x;
    const int e0 = blockIdx.x * EB;
    const int lane = t & 63;
    const int w    = t >> 6;
    const int l15  = lane & 15;
    const int q    = lane >> 4;
    const int ns   = w * 32;

    short8 bb[4][2];
    short8 a[4];
    f32x4 acc[2][4];
    float2 mreg2[4][4];

    // preload GEMM1 kc=0..3 B-frags (independent of everything)
#pragma unroll
    for (int kc = 0; kc < 4; ++kc)
#pragma unroll
        for (int nt = 0; nt < 2; ++nt)
            bb[kc][nt] = *(const short8*)&eW1f[(((w * 2 + nt) * 9 + kc) * 64 + lane) * 8];

    // P1: stage BOTH h[row]->sX and h[col]->sB in one burst.
    // Per-thread redundant perm/eidx loads (L1 broadcast) -> no index barrier.
    {
        int pe[4], rr[4], cc[4];
#pragma unroll
        for (int it = 0; it < 4; ++it) pe[it] = perm[e0 + (t >> 4) + it * 16];
#pragma unroll
        for (int it = 0; it < 4; ++it) { rr[it] = eidx[pe[it]]; cc[it] = eidx[NEDGE + pe[it]]; }
        const int c16 = t & 15;
#pragma unroll
        for (int it = 0; it < 4; ++it) {
            int e = (t >> 4) + it * 16;
            *(uint4*)&sX[e * PX + c16 * 8] = *(const uint4*)&hbf[(long)rr[it] * HID + c16 * 8];
            *(uint4*)&sB[e * PX + c16 * 8] = *(const uint4*)&hbf[(long)cc[it] * HID + c16 * 8];
        }
    }
    // P0: t<64 index table + geometry (consumed after B2)
    if (t < EB) {
        int e = perm[e0 + t];
        int r = eidx[e], c = eidx[NEDGE + e];
        rci[t] = r; rci[EB + t] = c;
        ea_s[t] = ea[e];
        float dx = pos[(long)r * 3 + 0] - pos[(long)c * 3 + 0];
        float dy = pos[(long)r * 3 + 1] - pos[(long)c * 3 + 1];
        float dz = pos[(long)r * 3 + 2] - pos[(long)c * 3 + 2];
        float rn = fmaxf(sqrtf(dx * dx + dy * dy + dz * dz), 1e-8f);
        rad[t][0] = dx; rad[t][1] = dy; rad[t][2] = dz; rad[t][3] = rn;
    }
    __syncthreads();   // B2: staging + index tables visible

    // P2: GEMM1 all 9 kc uninterrupted (kc0-3 from sX, kc4-7 from sB, kc8 regs)
#pragma unroll
    for (int nt = 0; nt < 2; ++nt) {
        float bv = eb1[ns + nt * 16 + l15];
#pragma unroll
        for (int mt = 0; mt < 4; ++mt)
            for (int r = 0; r < 4; ++r) acc[nt][mt][r] = bv;
    }
#pragma unroll
    for (int kc = 0; kc < 4; ++kc) {
#pragma unroll
        for (int mt = 0; mt < 4; ++mt)
            a[mt] = *(const short8*)&sX[(mt * 16 + l15) * PX + kc * 32 + q * 8];
#pragma unroll
        for (int nt = 0; nt < 2; ++nt)
#pragma unroll
            for (int mt = 0; mt < 4; ++mt)
                acc[nt][mt] = __builtin_amdgcn_mfma_f32_16x16x32_bf16(a[mt], bb[kc][nt], acc[nt][mt], 0, 0, 0);
    }
#pragma unroll
    for (int kc = 0; kc < 4; ++kc)
#pragma unroll
        for (int nt = 0; nt < 2; ++nt)
            bb[kc][nt] = *(const short8*)&eW1f[(((w * 2 + nt) * 9 + kc + 4) * 64 + lane) * 8];
#pragma unroll
    for (int kc = 0; kc < 4; ++kc) {
#pragma unroll
        for (int mt = 0; mt < 4; ++mt)
            a[mt] = *(const short8*)&sB[(mt * 16 + l15) * PX + kc * 32 + q * 8];
#pragma unroll
        for (int nt = 0; nt < 2; ++nt)
#pragma unroll
            for (int mt = 0; mt < 4; ++mt)
                acc[nt][mt] = __builtin_amdgcn_mfma_f32_16x16x32_bf16(a[mt], bb[kc][nt], acc[nt][mt], 0, 0, 0);
    }
    {
        short8 b8[2];
#pragma unroll
        for (int nt = 0; nt < 2; ++nt)
            b8[nt] = *(const short8*)&eW1f[(((w * 2 + nt) * 9 + 8) * 64 + lane) * 8];
#pragma unroll
        for (int mt = 0; mt < 4; ++mt) {
            int row = mt * 16 + l15;
            short8 a8;
#pragma unroll
            for (int j = 0; j < 8; ++j) a8[j] = 0;
            if (q == 0) {
                a8[0] = (short)f2bf(rad[row][3]);
                a8[1] = (short)f2bf(ea_s[row]);
            }
            a[mt] = a8;
        }
#pragma unroll
        for (int nt = 0; nt < 2; ++nt)
#pragma unroll
            for (int mt = 0; mt < 4; ++mt)
                acc[nt][mt] = __builtin_amdgcn_mfma_f32_16x16x32_bf16(a[mt], b8[nt], acc[nt][mt], 0, 0, 0);
    }
    // preload GEMM2 B-frags
#pragma unroll
    for (int kc = 0; kc < 4; ++kc)
#pragma unroll
        for (int nt = 0; nt < 2; ++nt)
            bb[kc][nt] = *(const short8*)&eW2f[(((w * 2 + nt) * 4 + kc) * 64 + lane) * 8];
    __syncthreads();   // B4a: all GEMM1 reads of sX/sB done -> epilogue may overwrite sB

    // GEMM1 epilogue: silu -> sB (interleaved col pairs)
#pragma unroll
    for (int mt = 0; mt < 4; ++mt)
#pragma unroll
        for (int r = 0; r < 4; ++r) {
            float2 v = silu2(acc[0][mt][r], acc[1][mt][r]);
            *(unsigned int*)&sB[(mt * 16 + q * 4 + r) * PX + ns + 2 * l15] = pkbf(v);
        }
    __syncthreads();   // B5

    // P5: GEMM2: sB @ eW2f -> silu = m (float2 regs + interleaved bf16 into sX)
#pragma unroll
    for (int nt = 0; nt < 2; ++nt) {
        float bv = eb2[ns + nt * 16 + l15];
#pragma unroll
        for (int mt = 0; mt < 4; ++mt)
            for (int r = 0; r < 4; ++r) acc[nt][mt][r] = bv;
    }
#pragma unroll
    for (int kc = 0; kc < 4; ++kc) {
#pragma unroll
        for (int mt = 0; mt < 4; ++mt)
            a[mt] = *(const short8*)&sB[(mt * 16 + l15) * PX + kc * 32 + q * 8];
#pragma unroll
        for (int nt = 0; nt < 2; ++nt)
#pragma unroll
            for (int mt = 0; mt < 4; ++mt)
                acc[nt][mt] = __builtin_amdgcn_mfma_f32_16x16x32_bf16(a[mt], bb[kc][nt], acc[nt][mt], 0, 0, 0);
    }
    // preload GEMM3 B-frags
#pragma unroll
    for (int kc = 0; kc < 4; ++kc)
#pragma unroll
        for (int nt = 0; nt < 2; ++nt)
            bb[kc][nt] = *(const short8*)&cW1f[(((w * 2 + nt) * 4 + kc) * 64 + lane) * 8];
#pragma unroll
    for (int mt = 0; mt < 4; ++mt)
#pragma unroll
        for (int r = 0; r < 4; ++r) {
            float2 v = silu2(acc[0][mt][r], acc[1][mt][r]);
            mreg2[mt][r] = v;
            *(unsigned int*)&sX[(mt * 16 + q * 4 + r) * PX + ns + 2 * l15] = pkbf(v);
        }
    __syncthreads();   // B6

    // P6: GEMM3: m @ cW1f -> silu -> dot(cW2) -> part
#pragma unroll
    for (int nt = 0; nt < 2; ++nt) {
        float bv = cb1[ns + nt * 16 + l15];
#pragma unroll
        for (int mt = 0; mt < 4; ++mt)
            for (int r = 0; r < 4; ++r) acc[nt][mt][r] = bv;
    }
#pragma unroll
    for (int kc = 0; kc < 4; ++kc) {
#pragma unroll
        for (int mt = 0; mt < 4; ++mt)
            a[mt] = *(const short8*)&sX[(mt * 16 + l15) * PX + kc * 32 + q * 8];
#pragma unroll
        for (int nt = 0; nt < 2; ++nt)
#pragma unroll
            for (int mt = 0; mt < 4; ++mt)
                acc[nt][mt] = __builtin_amdgcn_mfma_f32_16x16x32_bf16(a[mt], bb[kc][nt], acc[nt][mt], 0, 0, 0);
    }
    {
        float cw0 = cW2[ns + l15];
        float cw1 = cW2[ns + 16 + l15];
#pragma unroll
        for (int mt = 0; mt < 4; ++mt) {
            float p[4];
            for (int r = 0; r < 4; ++r) {
                float2 s = silu2(acc[0][mt][r], acc[1][mt][r]);
                p[r] = s.x * cw0 + s.y * cw1;
            }
            for (int mask = 1; mask < 16; mask <<= 1)
                for (int r = 0; r < 4; ++r) p[r] += __shfl_xor(p[r], mask);
            if (l15 == 0)
                for (int r = 0; r < 4; ++r) part[mt * 16 + q * 4 + r][w] = p[r];
        }
    }
    __syncthreads();   // B7

    // P7: fp32 m dump as float2 (waves 0,1 -> sX, waves 2,3 -> sB) + pos atomics
    {
        float2* dst = (w < 2) ? (float2*)sX : (float2*)sB;
        int cp = w * 16 + l15 - ((w < 2) ? 0 : 32);
#pragma unroll
        for (int mt = 0; mt < 4; ++mt)
#pragma unroll
            for (int r = 0; r < 4; ++r)
                dst[(mt * 16 + q * 4 + r) * 34 + cp] = mreg2[mt][r];
    }
    if (t < EB) {
        float cd  = part[t][0] + part[t][1] + part[t][2] + part[t][3] + cb2[0];
        float inv = cd / rad[t][3];
        int r = rci[t];
        atomicAdd(&outpos[(long)r * 3 + 0], inv * rad[t][0]);
        atomicAdd(&outpos[(long)r * 3 + 1], inv * rad[t][1]);
        atomicAdd(&outpos[(long)r * 3 + 2], inv * rad[t][2]);
    }
    __syncthreads();   // B8

    // P8: run-merged agg atomics: 2 threads/col, 32-edge runs (physical cols)
    {
        int j = t >> 1, k = t & 1;                 // physical col j, edge half k
        const float2* srcf = (j < 64) ? (const float2*)sX : (const float2*)sB;
        int cp = (j & 63) >> 1;
        int comp = j & 1;
        float s = 0.0f;
        int prev = rci[32 * k];
        for (int e = 32 * k; e < 32 * k + 32; ++e) {
            int rr = rci[e];
            if (rr != prev) {
                atomicAdd(&aggout[(long)prev * HID + j], s);
                s = 0.0f; prev = rr;
            }
            float2 v = srcf[e * 34 + cp];
            s += comp ? v.y : v.x;
        }
        atomicAdd(&aggout[(long)prev * HID + j], s);
    }
}

// ------------------------------------------------------------------ node phase (agg aliases out h-region)
__global__ __launch_bounds__(256)
void egnn_node(const float* h, const short* hbf, const float* agg,
               const float* nb1, const float* nb2,
               const short* nW1f, const short* nW2f,
               float* out)
{
    __shared__ __align__(16) short sA[EB * PN];
    __shared__ __align__(16) short sB2[EB * PX];

    const int t  = threadIdx.x;
    const int n0 = blockIdx.x * EB;

    for (int i = t; i < EB * 16; i += 256) {
        int e = i >> 4, uu = i & 15;
        int nd = n0 + e; if (nd >= NNODE) nd = NNODE - 1;
        *(uint4*)&sA[e * PN + uu * 8] = *(const uint4*)&hbf[(long)nd * HID + uu * 8];
    }
    for (int i = t; i < EB * 32; i += 256) {
        int e = i >> 5, uu = i & 31;
        int nd = n0 + e; if (nd >= NNODE) nd = NNODE - 1;
        const float4 v = *(const float4*)&agg[(long)nd * HID + uu * 4];
        unsigned short hx = f2bf(v.x), hy = f2bf(v.y), hz = f2bf(v.z), hw = f2bf(v.w);
        *(uint2*)&sA[e * PN + HID + uu * 4] =
            make_uint2(hx | ((unsigned int)hy << 16), hz | ((unsigned int)hw << 16));
        unsigned int l0 = pkbf(make_float2(v.x - bf2f(hx), v.y - bf2f(hy)));
        unsigned int l1 = pkbf(make_float2(v.z - bf2f(hz), v.w - bf2f(hw)));
        *(uint2*)&sA[e * PN + 2 * HID + uu * 4] = make_uint2(l0, l1);
    }
    __syncthreads();

    const int lane = t & 63;
    const int w    = t >> 6;
    const int l15  = lane & 15;
    const int q    = lane >> 4;
    const int ns   = w * 32;

    f32x4 acc[2][4];
    short8 a[4], b[2];

#pragma unroll
    for (int nt = 0; nt < 2; ++nt) {
        float bv = nb1[ns + nt * 16 + l15];
#pragma unroll
        for (int mt = 0; mt < 4; ++mt)
            for (int r = 0; r < 4; ++r) acc[nt][mt][r] = bv;
    }
    for (int kc = 0; kc < 12; ++kc) {
#pragma unroll
        for (int mt = 0; mt < 4; ++mt)
            a[mt] = *(const short8*)&sA[(mt * 16 + l15) * PN + kc * 32 + q * 8];
#pragma unroll
        for (int nt = 0; nt < 2; ++nt)
            b[nt] = *(const short8*)&nW1f[(((w * 2 + nt) * 12 + kc) * 64 + lane) * 8];
#pragma unroll
        for (int nt = 0; nt < 2; ++nt)
#pragma unroll
            for (int mt = 0; mt < 4; ++mt)
                acc[nt][mt] = __builtin_amdgcn_mfma_f32_16x16x32_bf16(a[mt], b[nt], acc[nt][mt], 0, 0, 0);
    }
#pragma unroll
    for (int mt = 0; mt < 4; ++mt)
#pragma unroll
        for (int r = 0; r < 4; ++r) {
            float2 v = silu2(acc[0][mt][r], acc[1][mt][r]);
            *(unsigned int*)&sB2[(mt * 16 + q * 4 + r) * PX + ns + 2 * l15] = pkbf(v);
        }
    __syncthreads();

#pragma unroll
    for (int nt = 0; nt < 2; ++nt) {
        float bv = nb2[ns + nt * 16 + l15];
#pragma unroll
        for (int mt = 0; mt < 4; ++mt)
            for (int r = 0; r < 4; ++r) acc[nt][mt][r] = bv;
    }
    for (int kc = 0; kc < 4; ++kc) {
#pragma unroll
        for (int mt = 0; mt < 4; ++mt)
            a[mt] = *(const short8*)&sB2[(mt * 16 + l15) * PX + kc * 32 + q * 8];
#pragma unroll
        for (int nt = 0; nt < 2; ++nt)
            b[nt] = *(const short8*)&nW2f[(((w * 2 + nt) * 4 + kc) * 64 + lane) * 8];
#pragma unroll
        for (int nt = 0; nt < 2; ++nt)
#pragma unroll
            for (int mt = 0; mt < 4; ++mt)
                acc[nt][mt] = __builtin_amdgcn_mfma_f32_16x16x32_bf16(a[mt], b[nt], acc[nt][mt], 0, 0, 0);
    }
#pragma unroll
    for (int nt = 0; nt < 2; ++nt)
#pragma unroll
        for (int mt = 0; mt < 4; ++mt)
            for (int r = 0; r < 4; ++r) {
                int m  = mt * 16 + q * 4 + r;
                int nd = n0 + m;
                if (nd < NNODE) {
                    int n = ns + nt * 16 + l15;
                    out[(long)nd * HID + n] = h[(long)nd * HID + n] + acc[nt][mt][r];
                }
            }
}

// ------------------------------------------------------------------ launch
extern "C" void kernel_launch(void* const* d_in, const int* in_sizes, int n_in,
                              void* d_out, int out_size, void* d_ws, size_t ws_size,
                              hipStream_t stream)
{
    const float* h    = (const float*)d_in[0];
    const float* pos  = (const float*)d_in[1];
    const float* ea   = (const float*)d_in[2];
    const int*   eidx = (const int*)d_in[3];
    const float* eW1  = (const float*)d_in[4];
    const float* eb1  = (const float*)d_in[5];
    const float* eW2  = (const float*)d_in[6];
    const float* eb2  = (const float*)d_in[7];
    const float* nW1  = (const float*)d_in[8];
    const float* nb1  = (const float*)d_in[9];
    const float* nW2  = (const float*)d_in[10];
    const float* nb2  = (const float*)d_in[11];
    const float* cW1  = (const float*)d_in[12];
    const float* cb1  = (const float*)d_in[13];
    const float* cW2  = (const float*)d_in[14];
    const float* cb2  = (const float*)d_in[15];

    float* out    = (float*)d_out;
    float* outpos = out + (long)NNODE * HID;

    char* ws = (char*)d_ws;
    short* wsw    = (short*)ws;
    short* hbf    = (short*)(ws + WS_HBF);
    int*   deg    = (int*)(ws + WS_DEG);
    int*   rowptr = (int*)(ws + WS_ROW);
    int*   cursor = (int*)(ws + WS_CUR);
    int*   bsum   = (int*)(ws + WS_BSUM);
    int*   perm   = (int*)(ws + WS_PERM);

    const short* eW1f = wsw;
    const short* eW2f = wsw + 4608 * 8;
    const short* cW1f = wsw + 6656 * 8;
    const short* nW1f = wsw + 8704 * 8;
    const short* nW2f = wsw + 14848 * 8;

    egnn_prep<<<(2616896 + 255) / 256, 256, 0, stream>>>(
        eW1, eW2, cW1, nW1, nW2, h, pos, wsw, hbf, deg, out);
    egnn_hist<<<(NEDGE / 4 + 255) / 256, 256, 0, stream>>>(eidx, deg);
    egnn_scan1<<<196, 256, 0, stream>>>(deg, rowptr, bsum);
    egnn_scanF<<<196, 256, 0, stream>>>(rowptr, bsum, cursor);
    egnn_scatter<<<(NEDGE + 255) / 256, 256, 0, stream>>>(eidx, cursor, perm);
    egnn_edge<<<NEDGE / EB, 256, 0, stream>>>(hbf, pos, ea, eidx, perm,
                                              eb1, eb2, cb1, cW2, cb2,
                                              eW1f, eW2f, cW1f, out, outpos);
    egnn_node<<<(NNODE + EB - 1) / EB, 256, 0, stream>>>(h, hbf, out, nb1, nb2,
                                                         nW1f, nW2f, out);
}